// Round 8
// baseline (364.749 us; speedup 1.0000x reference)
//
#include <hip/hip_runtime.h>
#include <hip/hip_bf16.h>
#include <stdint.h>

typedef short s16x8 __attribute__((ext_vector_type(8)));
typedef float f32x4 __attribute__((ext_vector_type(4)));
typedef int   i32x4 __attribute__((ext_vector_type(4)));
typedef unsigned int u32;
typedef unsigned short u16;

#define CCH 192
#define APITCH 200   // bf16 elems per LDS row; 400B pitch
#define NCODES 128
#define HALO 9
#define ROWS 82      // staged rows: tokens t0-9 .. t0+72
#define WE (3 * CCH * CCH)

__device__ __forceinline__ u16 f2b(float f) {
  u32 u = __builtin_bit_cast(u32, f);
  u = (u + 0x7fffu + ((u >> 16) & 1u)) >> 16;   // RNE
  return (u16)u;
}
__device__ __forceinline__ float b2f(u16 h) {
  return __builtin_bit_cast(float, ((u32)h) << 16);
}
__device__ __forceinline__ i32x4 mksrsrc(const void* p) {
  u32 lo = (u32)(uintptr_t)p, hi = (u32)(((uintptr_t)p) >> 32);
  i32x4 r;
  r[0] = (int)lo;
  r[1] = (int)(hi & 0xffffu);   // stride 0
  r[2] = -1;                    // num_records = 0xFFFFFFFF (bounds check off)
  r[3] = 0x00020000;            // raw dword access
  return r;
}

// ---- x (B,C,T) f32 -> xt (B,T,C) bf16 ----
__global__ __launch_bounds__(256) void k_tin(const float* __restrict__ x, u16* __restrict__ xt,
                                             int B, int T) {
  __shared__ float tile[32][36];
  int nt = T >> 5;
  int bid = blockIdx.x;
  int b = bid / (6 * nt);
  int rem = bid % (6 * nt);
  int cb = rem / nt, tb = rem % nt;
  int tid = threadIdx.x;
  {
    int c = tid >> 3, seg = tid & 7;
    const float* src = x + ((size_t)b * CCH + cb * 32 + c) * T + tb * 32 + seg * 4;
    float4 v = *(const float4*)src;
    tile[c][seg * 4 + 0] = v.x; tile[c][seg * 4 + 1] = v.y;
    tile[c][seg * 4 + 2] = v.z; tile[c][seg * 4 + 3] = v.w;
  }
  __syncthreads();
  {
    int t = tid >> 3, cs = tid & 7;
    u16* dst = xt + ((size_t)b * T + tb * 32 + t) * CCH + cb * 32 + cs * 4;
    ushort4 o;
    o.x = f2b(tile[cs * 4 + 0][t]); o.y = f2b(tile[cs * 4 + 1][t]);
    o.z = f2b(tile[cs * 4 + 2][t]); o.w = f2b(tile[cs * 4 + 3][t]);
    *(ushort4*)dst = o;
  }
}

// ---- weights (O,I,3) f32 -> (3,O,I) bf16 ----
__global__ __launch_bounds__(256) void k_wconv(const float* __restrict__ w, u16* __restrict__ dst) {
  int i = blockIdx.x * 256 + threadIdx.x;
  if (i >= 3 * CCH * CCH) return;
  int k = i / (CCH * CCH);
  int rem = i - k * (CCH * CCH);
  int o = rem / CCH, ii = rem - o * CCH;
  dst[i] = f2b(w[(o * CCH + ii) * 3 + k]);
}

// ---- emb (K,C) f32 -> bf16 + ||e||^2 f32 ----
__global__ __launch_bounds__(64) void k_emb(const float* __restrict__ emb, u16* __restrict__ embb,
                                            float* __restrict__ e2) {
  int code = blockIdx.x, lane = threadIdx.x;
  float s = 0.f;
  for (int j = lane * 3; j < lane * 3 + 3; ++j) {
    float v = emb[code * CCH + j];
    embb[code * CCH + j] = f2b(v);
    s += v * v;
  }
  #pragma unroll
  for (int m = 1; m < 64; m <<= 1) s += __shfl_xor(s, m, 64);
  if (lane == 0) e2[code] = s;
}

__global__ void k_zero(int* hist, double* dsum) {
  int t = threadIdx.x;
  if (t < NCODES) hist[t] = 0;
  if (t == 0) *dsum = 0.0;
}

// ======== inline-asm pipelined conv: the compiler cannot sink asm-volatile loads ========
// Weight loads: buffer_load_dwordx4, SRSRC, lane voffset, SGPR soffset (kk,nf), imm = cb*64.
// Act loads: ds_read_b128, lane address, imm = (row*APITCH + cb*32)*2.
// Waits are hand-counted: vmcnt(9) leaves the 9 newest (next cb's weights) in flight;
// lgkmcnt(F) leaves the F newest (next step's act frags). sched_barrier(0) after each wait
// (rule: hipcc hoists register-only MFMA past inline-asm waitcnt otherwise).

template<int CW, int CB, int J>
__device__ __forceinline__ void wload(u32 voff, i32x4 rs, u32 stoff, s16x8 (&w)[2][9]) {
  constexpr int kk = J / 3, nf = J - kk * 3;
  asm volatile("buffer_load_dwordx4 %0, %1, %2, %3 offen offset:%4"
               : "=v"(w[CW][J])
               : "v"(voff), "s"(rs), "s"(stoff + (u32)(kk * 73728 + nf * 6144)), "i"(CB * 64));
  if constexpr (J < 8) wload<CW, CB, J + 1>(voff, rs, stoff, w);
}

template<int F, int ORIG, int CA, int IT, int M>
__device__ __forceinline__ void aload(u32 aaddr, s16x8 (&a)[2][F]) {
  constexpr int cb = IT / 3, k = IT - cb * 3;
  constexpr int imm = ((ORIG - 1 + 16 * M + k) * APITCH + cb * 32) * 2;
  asm volatile("ds_read_b128 %0, %1 offset:%2" : "=v"(a[CA][M]) : "v"(aaddr), "i"(imm));
  if constexpr (M + 1 < F) aload<F, ORIG, CA, IT, M + 1>(aaddr, a);
}

template<int F, int ORIG, int IT>
__device__ __forceinline__ void cstep(u32 aaddr, u32 voff, i32x4 rs, u32 stoff,
                                      s16x8 (&w)[2][9], s16x8 (&a)[2][F], f32x4 (&acc)[F][3]) {
  constexpr int cb = IT / 3, k = IT - cb * 3;
  constexpr int cw = cb & 1, ca = IT & 1;
  if constexpr (k == 0 && cb < 5)
    wload<cw ^ 1, cb + 1, 0>(voff, rs, stoff, w);
  if constexpr (IT < 17)
    aload<F, ORIG, ca ^ 1, IT + 1, 0>(aaddr, a);
  if constexpr (k == 0 && cb < 5) {
    if constexpr (F == 5) asm volatile("s_waitcnt vmcnt(9) lgkmcnt(5)");
    else                  asm volatile("s_waitcnt vmcnt(9) lgkmcnt(4)");
  } else if constexpr (k == 0) {
    if constexpr (F == 5) asm volatile("s_waitcnt vmcnt(0) lgkmcnt(5)");
    else                  asm volatile("s_waitcnt vmcnt(0) lgkmcnt(4)");
  } else if constexpr (IT < 17) {
    if constexpr (F == 5) asm volatile("s_waitcnt lgkmcnt(5)");
    else                  asm volatile("s_waitcnt lgkmcnt(4)");
  } else {
    asm volatile("s_waitcnt lgkmcnt(0)");
  }
  __builtin_amdgcn_sched_barrier(0);
  #pragma unroll
  for (int m = 0; m < F; ++m)
    #pragma unroll
    for (int nf = 0; nf < 3; ++nf)
      acc[m][nf] = __builtin_amdgcn_mfma_f32_16x16x32_bf16(a[ca][m], w[cw][k * 3 + nf], acc[m][nf], 0, 0, 0);
  if constexpr (IT + 1 < 18)
    cstep<F, ORIG, IT + 1>(aaddr, voff, rs, stoff, w, a, acc);
}

template<int F, int ORIG>
__device__ __forceinline__ void conv_compute(const u16* lds_act, i32x4 rs, u32 stoff,
                                             int oB, int lr, int lg, f32x4 (&acc)[F][3]) {
  u32 aaddr = (u32)(uintptr_t)lds_act + (u32)((lr * APITCH + lg * 8) * 2);
  u32 voff = (u32)(((oB + lr) * CCH + lg * 8) * 2);
  s16x8 w[2][9];
  s16x8 a[2][F];
  wload<0, 0, 0>(voff, rs, stoff, w);
  aload<F, ORIG, 0, 0, 0>(aaddr, a);
  cstep<F, ORIG, 0>(aaddr, voff, rs, stoff, w, a, acc);
}

// ---- one conv stage, IN-PLACE: compute; barrier; write rows [ORIG, ORIG+16F); barrier ----
template<int F, int ORIG, bool RELU>
__device__ __forceinline__ void conv_stage(u16* __restrict__ buf, i32x4 rs, u32 stoff,
                                           const float* __restrict__ bias,
                                           int wv, int lr, int lg, int t0, int T, bool edge) {
  const int oB = wv * 48;
  f32x4 acc[F][3];
  #pragma unroll
  for (int m = 0; m < F; ++m)
    #pragma unroll
    for (int n = 0; n < 3; ++n) acc[m][n] = f32x4{0.f, 0.f, 0.f, 0.f};
  conv_compute<F, ORIG>(buf, rs, stoff, oB, lr, lg, acc);
  float bv[3];
  #pragma unroll
  for (int nf = 0; nf < 3; ++nf) bv[nf] = bias[oB + nf * 16 + lr];
  __syncthreads();                        // all waves done READING buf
  if (!edge) {
    #pragma unroll
    for (int m = 0; m < F; ++m) {
      #pragma unroll
      for (int nf = 0; nf < 3; ++nf) {
        int o = oB + nf * 16 + lr;
        #pragma unroll
        for (int r = 0; r < 4; ++r) {
          int row = ORIG + 16 * m + lg * 4 + r;
          float v = acc[m][nf][r] + bv[nf];
          if (RELU) v = fmaxf(v, 0.f);
          buf[row * APITCH + o] = f2b(v);
        }
      }
    }
  } else {
    #pragma unroll
    for (int m = 0; m < F; ++m) {
      #pragma unroll
      for (int nf = 0; nf < 3; ++nf) {
        int o = oB + nf * 16 + lr;
        #pragma unroll
        for (int r = 0; r < 4; ++r) {
          int row = ORIG + 16 * m + lg * 4 + r;
          int tok = t0 - HALO + row;
          float v = acc[m][nf][r] + bv[nf];
          if (RELU) v = fmaxf(v, 0.f);
          if (tok < 0 || tok >= T) v = 0.f;   // reference zero-pads EVERY conv at sequence edges
          buf[row * APITCH + o] = f2b(v);
        }
      }
    }
  }
  __syncthreads();                        // writes visible
}

// ---- VQ pipelined loads ----
template<int CE, int CB, int J>
__device__ __forceinline__ void eload(u32 voffE, i32x4 rsE, s16x8 (&eb)[2][8]) {
  asm volatile("buffer_load_dwordx4 %0, %1, %2, %3 offen offset:%4"
               : "=v"(eb[CE][J]) : "v"(voffE), "s"(rsE), "s"((u32)(J * 6144)), "i"(CB * 64));
  if constexpr (J < 7) eload<CE, CB, J + 1>(voffE, rsE, eb);
}

template<int CB>
__device__ __forceinline__ void vqstep(u32 zaddr, u32 voffE, i32x4 rsE,
                                       s16x8 (&az)[2], s16x8 (&eb)[2][8], f32x4 (&vacc)[8]) {
  constexpr int ce = CB & 1;
  if constexpr (CB < 5) {
    eload<ce ^ 1, CB + 1, 0>(voffE, rsE, eb);
    asm volatile("ds_read_b128 %0, %1 offset:%2" : "=v"(az[ce ^ 1]) : "v"(zaddr), "i"((CB + 1) * 64));
    asm volatile("s_waitcnt vmcnt(8) lgkmcnt(1)");
  } else {
    asm volatile("s_waitcnt vmcnt(0) lgkmcnt(0)");
  }
  __builtin_amdgcn_sched_barrier(0);
  #pragma unroll
  for (int nf = 0; nf < 8; ++nf)
    vacc[nf] = __builtin_amdgcn_mfma_f32_16x16x32_bf16(az[ce], eb[ce][nf], vacc[nf], 0, 0, 0);
  if constexpr (CB + 1 < 6) vqstep<CB + 1>(zaddr, voffE, rsE, az, eb, vacc);
}

// ---- fully fused: stage x tile -> enc1 -> enc2 -> VQ -> dec1 -> dec2 -> dec3 -> f32 (B,C,T) out ----
__global__ __launch_bounds__(256, 2) void k_fused(
    const u16* __restrict__ xt, const u16* __restrict__ wts,
    const float* __restrict__ eb1, const float* __restrict__ eb2,
    const float* __restrict__ db1, const float* __restrict__ db2, const float* __restrict__ db3,
    const u16* __restrict__ embb, const float* __restrict__ e2,
    int* __restrict__ hist, double* __restrict__ dsum,
    float* __restrict__ xhat, int T) {
  __shared__ __align__(16) u16 act[ROWS * APITCH];   // 32800 B, single in-place buffer
  __shared__ int hs[NCODES];
  __shared__ float wsum[4];
  const int tid = threadIdx.x;
  const int wv = tid >> 6, lane = tid & 63, lr = lane & 15, lg = lane >> 4;
  const int bid = blockIdx.x;
  const int b = bid >> 7, tile = bid & 127;   // T/64 = 128 tiles per batch
  const int t0 = tile * 64;
  const bool edge = (tile == 0) || (tile == 127);
  if (tid < NCODES) hs[tid] = 0;

  const i32x4 rs = mksrsrc(wts);

  // ---- stage x rows t0-9 .. t0+72 (82 rows x 192 ch) ----
  {
    const u16* src = xt + (size_t)b * T * CCH;
    uint4 v[8]; int ra[8], sa[8];
    #pragma unroll
    for (int i = 0; i < 8; ++i) {
      unsigned s = tid + i * 256u;
      int row = (int)(s / 24u), seg = (int)(s - (unsigned)row * 24u);
      ra[i] = row; sa[i] = seg;
      int tok = t0 - HALO + row;
      uint4 t = {0u, 0u, 0u, 0u};
      if (s < ROWS * 24u && tok >= 0 && tok < T)
        t = *(const uint4*)(src + (size_t)tok * CCH + seg * 8);
      v[i] = t;
    }
    #pragma unroll
    for (int i = 0; i < 8; ++i) {
      if (tid + i * 256u < ROWS * 24u)
        *(uint4*)(act + ra[i] * APITCH + sa[i] * 8) = v[i];
    }
  }
  __syncthreads();

  conv_stage<5, 1, true >(act, rs, 0u * WE * 2u, eb1, wv, lr, lg, t0, T, edge);  // h1
  conv_stage<5, 1, false>(act, rs, 1u * WE * 2u, eb2, wv, lr, lg, t0, T, edge);  // z_e

  // ---- VQ on LDS z_e (read-only), own tokens = rows HALO..HALO+63; wave wv owns 16 tokens ----
  {
    const int row = HALO + wv * 16 + lr;
    const u16* zbase = act + row * APITCH;
    // ||z||^2 first (keeps compiler LDS reads out of the counted region)
    float z2 = 0.f;
    const u16* zr = zbase + lg * 48;
    #pragma unroll
    for (int j = 0; j < 48; j += 8) {
      s16x8 vv = *(const s16x8*)(zr + j);
      #pragma unroll
      for (int e = 0; e < 8; ++e) { float f = b2f((u16)vv[e]); z2 += f * f; }
    }
    z2 += __shfl_xor(z2, 16, 64);
    z2 += __shfl_xor(z2, 32, 64);

    f32x4 vacc[8];
    #pragma unroll
    for (int nf = 0; nf < 8; ++nf) vacc[nf] = f32x4{0.f, 0.f, 0.f, 0.f};
    {
      const i32x4 rsE = mksrsrc(embb);
      u32 zaddr = (u32)(uintptr_t)act + (u32)((row * APITCH + lg * 8) * 2);
      u32 voffE = (u32)((lr * CCH + lg * 8) * 2);
      s16x8 az[2];
      s16x8 eb[2][8];
      eload<0, 0, 0>(voffE, rsE, eb);
      asm volatile("ds_read_b128 %0, %1 offset:0" : "=v"(az[0]) : "v"(zaddr));
      vqstep<0>(zaddr, voffE, rsE, az, eb, vacc);
    }
    float smin[4]; int imin[4];
    #pragma unroll
    for (int r = 0; r < 4; ++r) { smin[r] = 3.4e38f; imin[r] = 0; }
    #pragma unroll
    for (int nf = 0; nf < 8; ++nf) {
      int code = nf * 16 + lr;
      float ev = e2[code];
      #pragma unroll
      for (int r = 0; r < 4; ++r) {
        float sc = ev - 2.f * vacc[nf][r];
        if (sc < smin[r]) { smin[r] = sc; imin[r] = code; }
      }
    }
    #pragma unroll
    for (int m = 1; m < 16; m <<= 1) {
      #pragma unroll
      for (int r = 0; r < 4; ++r) {
        float so = __shfl_xor(smin[r], m, 64);
        int io = __shfl_xor(imin[r], m, 64);
        if (so < smin[r] || (so == smin[r] && io < imin[r])) { smin[r] = so; imin[r] = io; }
      }
    }
    float z2t[4];
    #pragma unroll
    for (int r = 0; r < 4; ++r) z2t[r] = __shfl(z2, lg * 4 + r, 64);
    float dpart = 0.f;
    if (lr == 0) {
      #pragma unroll
      for (int r = 0; r < 4; ++r) {
        dpart += z2t[r] + smin[r];
        atomicAdd(&hs[imin[r]], 1);
      }
    }
    #pragma unroll
    for (int m = 1; m < 64; m <<= 1) dpart += __shfl_xor(dpart, m, 64);
    if (lane == 0) wsum[wv] = dpart;
  }
  // VQ reads complete before dec1's internal (post-compute) barrier -> safe.

  conv_stage<5, 1, true >(act, rs, 2u * WE * 2u, db1, wv, lr, lg, t0, T, edge);  // h

  // flush VQ stats (hs/wsum complete before dec1's barriers)
  if (tid == 0) {
    double tot = (double)wsum[0] + (double)wsum[1] + (double)wsum[2] + (double)wsum[3];
    atomicAdd(dsum, tot);
  }
  if (tid < NCODES && hs[tid] > 0) atomicAdd(&hist[tid], hs[tid]);

  conv_stage<5, 1, true >(act, rs, 3u * WE * 2u, db2, wv, lr, lg, t0, T, edge);  // h2

  // ---- stage 5: x_hat rows 9..72 (exactly own 64 tokens), acc in regs ----
  const int oB = wv * 48;
  f32x4 acc5[4][3];
  #pragma unroll
  for (int m = 0; m < 4; ++m)
    #pragma unroll
    for (int n = 0; n < 3; ++n) acc5[m][n] = f32x4{0.f, 0.f, 0.f, 0.f};
  conv_compute<4, 9>(act, rs, 4u * WE * 2u, oB, lr, lg, acc5);
  float bv[3];
  #pragma unroll
  for (int nf = 0; nf < 3; ++nf) bv[nf] = db3[oB + nf * 16 + lr];

  // ---- two-pass f32 transpose out (96 channels per pass; ft = 96*66*4 = 25 KB <= act) ----
  float* ft = (float*)act;             // reuse act buffer
  float* dstb = xhat + (size_t)b * CCH * T + t0;
  #pragma unroll
  for (int p = 0; p < 2; ++p) {
    __syncthreads();                   // p=0: all done reading act; p=1: stores of pass 0 done
    if ((wv >> 1) == p) {
      #pragma unroll
      for (int m = 0; m < 4; ++m) {
        #pragma unroll
        for (int nf = 0; nf < 3; ++nf) {
          int o = oB + nf * 16 + lr - p * 96;
          #pragma unroll
          for (int r = 0; r < 4; ++r) {
            int tl = 16 * m + lg * 4 + r;
            ft[o * 66 + tl] = acc5[m][nf][r] + bv[nf];
          }
        }
      }
    }
    __syncthreads();
    for (int s = tid; s < 96 * 64; s += 256) {
      int o = s >> 6, tl = s & 63;
      dstb[(size_t)(o + p * 96) * T + tl] = ft[o * 66 + tl];
    }
  }
}

__global__ __launch_bounds__(128) void k_fin(const int* __restrict__ hist,
                                             const double* __restrict__ dsum,
                                             float* __restrict__ out, int N, int ppos) {
  __shared__ float H[NCODES];
  int t = threadIdx.x;
  float p = (float)hist[t] / (float)N;
  H[t] = p * logf(p + 1e-10f);
  __syncthreads();
  if (t == 0) {
    float s = 0.f;
    for (int i = 0; i < NCODES; ++i) s += H[i];
    out[ppos] = expf(-s);
    out[0] = (float)(1.25 * (*dsum) / ((double)N * (double)CCH));
  }
}

extern "C" void kernel_launch(void* const* d_in, const int* in_sizes, int n_in,
                              void* d_out, int out_size, void* d_ws, size_t ws_size,
                              hipStream_t stream) {
  const int B = 16, T = 8192, N = B * T;
  const float* x   = (const float*)d_in[0];
  const float* ew1 = (const float*)d_in[1];
  const float* eb1 = (const float*)d_in[2];
  const float* ew2 = (const float*)d_in[3];
  const float* eb2 = (const float*)d_in[4];
  const float* emb = (const float*)d_in[5];
  const float* dw1 = (const float*)d_in[6];
  const float* db1 = (const float*)d_in[7];
  const float* dw2 = (const float*)d_in[8];
  const float* db2 = (const float*)d_in[9];
  const float* dw3 = (const float*)d_in[10];
  const float* db3 = (const float*)d_in[11];

  char* ws = (char*)d_ws;
  const size_t actSz = (size_t)B * T * CCH * 2;
  u16* bufA = (u16*)ws;                                // xt
  u16* wts  = (u16*)(ws + actSz);
  u16* embb = (u16*)(ws + actSz + (size_t)5 * WE * 2);
  float* e2 = (float*)((char*)embb + (size_t)NCODES * CCH * 2);
  int* hist = (int*)((char*)e2 + 512);
  double* dsum = (double*)((char*)hist + 512);

  const int wblocks = (3 * CCH * CCH + 255) / 256;
  k_wconv<<<wblocks, 256, 0, stream>>>(ew1, wts);
  k_wconv<<<wblocks, 256, 0, stream>>>(ew2, wts + WE);
  k_wconv<<<wblocks, 256, 0, stream>>>(dw1, wts + 2 * WE);
  k_wconv<<<wblocks, 256, 0, stream>>>(dw2, wts + 3 * WE);
  k_wconv<<<wblocks, 256, 0, stream>>>(dw3, wts + 4 * WE);
  k_emb<<<NCODES, 64, 0, stream>>>(emb, embb, e2);
  k_zero<<<1, 256, 0, stream>>>(hist, dsum);
  k_tin<<<B * 6 * (T / 32), 256, 0, stream>>>(x, bufA, B, T);

  k_fused<<<B * (T / 64), 256, 0, stream>>>(bufA, wts, eb1, eb2, db1, db2, db3,
                                            embb, e2, hist, dsum, (float*)d_out + 1, T);
  k_fin<<<1, 128, 0, stream>>>(hist, dsum, (float*)d_out, N, out_size - 1);
}

// Round 10
// 339.780 us; speedup vs baseline: 1.0735x; 1.0735x over previous
//
#include <hip/hip_runtime.h>
#include <hip/hip_bf16.h>
#include <stdint.h>

typedef short s16x8 __attribute__((ext_vector_type(8)));
typedef float f32x4 __attribute__((ext_vector_type(4)));
typedef unsigned int u32;
typedef unsigned short u16;

#define CCH 192
#define APITCH 200     // u16 pitch of act rows (400 B)
#define NCODES 128
#define HALO 9
#define RPB 8216       // padded rows per batch in xtp: 12 lead + 8192 + 12 trail
#define LEAD 12
#define WCH 36864      // one weight chunk (cb): 3k x 192o x 32i bf16 = 36,864 B

__device__ __forceinline__ u16 f2b(float f) {
  u32 u = __builtin_bit_cast(u32, f);
  u = (u + 0x7fffu + ((u >> 16) & 1u)) >> 16;   // RNE
  return (u16)u;
}
__device__ __forceinline__ float b2f(u16 h) {
  return __builtin_bit_cast(float, ((u32)h) << 16);
}
__device__ __forceinline__ void gld16(const void* g, void* l) {
  __builtin_amdgcn_global_load_lds(
      (const __attribute__((address_space(1))) void*)g,
      (__attribute__((address_space(3))) void*)l, 16, 0, 0);
}

// ---- x (B,C,T) f32 -> xtp (padded rows, pitch 200) bf16 ----
__global__ __launch_bounds__(256) void k_tin(const float* __restrict__ x, u16* __restrict__ xtp,
                                             int B, int T) {
  __shared__ float tile[32][36];
  int nt = T >> 5;
  int bid = blockIdx.x;
  int b = bid / (6 * nt);
  int rem = bid % (6 * nt);
  int cb = rem / nt, tb = rem % nt;
  int tid = threadIdx.x;
  {
    int c = tid >> 3, seg = tid & 7;
    const float* src = x + ((size_t)b * CCH + cb * 32 + c) * T + tb * 32 + seg * 4;
    float4 v = *(const float4*)src;
    tile[c][seg * 4 + 0] = v.x; tile[c][seg * 4 + 1] = v.y;
    tile[c][seg * 4 + 2] = v.z; tile[c][seg * 4 + 3] = v.w;
  }
  __syncthreads();
  {
    int t = tid >> 3, cs = tid & 7;
    u16* dst = xtp + ((size_t)(b * RPB + LEAD + tb * 32 + t)) * APITCH + cb * 32 + cs * 4;
    ushort4 o;
    o.x = f2b(tile[cs * 4 + 0][t]); o.y = f2b(tile[cs * 4 + 1][t]);
    o.z = f2b(tile[cs * 4 + 2][t]); o.w = f2b(tile[cs * 4 + 3][t]);
    *(ushort4*)dst = o;
  }
}

// ---- zero the pad rows of xtp (12 lead + 12 trail per batch, full 400B rows) ----
__global__ __launch_bounds__(256) void k_padz(u16* __restrict__ xtp) {
  int b = blockIdx.x;
  for (int i = threadIdx.x; i < 24 * 25; i += 256) {
    int r = i / 25, c = i - (i / 25) * 25;
    int row = (r < 12) ? r : (RPB - 12 + (r - 12));
    uint4 z = {0u, 0u, 0u, 0u};
    *(uint4*)((char*)xtp + ((size_t)(b * RPB + row)) * 400 + c * 16) = z;
  }
}

// ---- weights (O,I,3) f32 -> chunked bf16 [cb][k][o][i32] (36,864 B per cb) ----
__global__ __launch_bounds__(256) void k_wconv(const float* __restrict__ w, u16* __restrict__ dst) {
  int i = blockIdx.x * 256 + threadIdx.x;
  if (i >= 3 * CCH * CCH) return;
  int cb = i / 18432;
  int r = i - cb * 18432;
  int k = r / 6144;
  int r2 = r - k * 6144;
  int o = r2 / 32, il = r2 - o * 32;
  dst[i] = f2b(w[(o * CCH + cb * 32 + il) * 3 + k]);
}

// ---- emb (K,C) f32 -> embp bf16 pitch 200 + ||e||^2 f32 ----
__global__ __launch_bounds__(64) void k_emb(const float* __restrict__ emb, u16* __restrict__ embp,
                                            float* __restrict__ e2) {
  int code = blockIdx.x, lane = threadIdx.x;
  float s = 0.f;
  for (int j = lane * 3; j < lane * 3 + 3; ++j) {
    float v = emb[code * CCH + j];
    embp[code * APITCH + j] = f2b(v);
    s += v * v;
  }
  if (lane < 8) embp[code * APITCH + 192 + lane] = 0;
  #pragma unroll
  for (int m = 1; m < 64; m <<= 1) s += __shfl_xor(s, m, 64);
  if (lane == 0) e2[code] = s;
}

__global__ void k_zero(int* hist, double* dsum) {
  int t = threadIdx.x;
  if (t < NCODES) hist[t] = 0;
  if (t == 0) *dsum = 0.0;
}

// ---- one conv stage: 6 chunk-steps (gld_lds stream, counted vmcnt, raw barriers), in-place epilogue ----
template<int G0, int F, int ORIG, bool RELU, bool ISSUE_LAST>
__device__ __forceinline__ void stage(const char* __restrict__ wtp, u16* __restrict__ act,
                                      u16 (*wb)[18432], const float* bv,
                                      int oB, int wv, int lane, int lr, int lg,
                                      int t0, int T, bool edge) {
  f32x4 acc[F][3];
  #pragma unroll
  for (int m = 0; m < F; ++m)
    #pragma unroll
    for (int n = 0; n < 3; ++n) acc[m][n] = f32x4{0.f, 0.f, 0.f, 0.f};
  // FIX (r9 bug): per-lane A-fragment row base includes lr*APITCH (lane lr = M-row in 16-block)
  const u16* arow = act + lr * APITCH + lg * 8;
  #pragma unroll
  for (int cb = 0; cb < 6; ++cb) {
    const int g = G0 + cb;
    if (cb < 5 || ISSUE_LAST) {          // issue chunk g+1 (+1 lookahead: race-free, 1 barrier/step)
      const char* src = wtp + (size_t)(g + 1) * WCH + (wv * 9) * 1024 + lane * 16;
      char* dst = (char*)wb[(g + 1) % 3] + (wv * 9) * 1024;
      #pragma unroll
      for (int j = 0; j < 9; ++j) gld16(src + j * 1024, dst + j * 1024);
      asm volatile("s_waitcnt vmcnt(9)" ::: "memory");   // chunk g (and anything older) complete
    } else {
      asm volatile("s_waitcnt vmcnt(0)" ::: "memory");
    }
    __builtin_amdgcn_sched_barrier(0);
    __builtin_amdgcn_s_barrier();
    const u16* wq = wb[g % 3];
    #pragma unroll
    for (int k = 0; k < 3; ++k) {
      s16x8 af[F];
      #pragma unroll
      for (int m = 0; m < F; ++m)
        af[m] = *(const s16x8*)(arow + (ORIG - 1 + 16 * m + k) * APITCH + cb * 32);
      #pragma unroll
      for (int nf = 0; nf < 3; ++nf) {
        s16x8 wf = *(const s16x8*)(wq + (k * CCH + oB + nf * 16 + lr) * 32 + lg * 8);
        #pragma unroll
        for (int m = 0; m < F; ++m)
          acc[m][nf] = __builtin_amdgcn_mfma_f32_16x16x32_bf16(af[m], wf, acc[m][nf], 0, 0, 0);
      }
    }
  }
  __builtin_amdgcn_s_barrier();          // E1: all waves done reading act
  if (!edge) {
    #pragma unroll
    for (int m = 0; m < F; ++m)
      #pragma unroll
      for (int nf = 0; nf < 3; ++nf) {
        int o = oB + nf * 16 + lr;
        #pragma unroll
        for (int r = 0; r < 4; ++r) {
          int row = ORIG + 16 * m + lg * 4 + r;
          float v = acc[m][nf][r] + bv[nf];
          if (RELU) v = fmaxf(v, 0.f);
          act[row * APITCH + o] = f2b(v);
        }
      }
  } else {
    #pragma unroll
    for (int m = 0; m < F; ++m)
      #pragma unroll
      for (int nf = 0; nf < 3; ++nf) {
        int o = oB + nf * 16 + lr;
        #pragma unroll
        for (int r = 0; r < 4; ++r) {
          int row = ORIG + 16 * m + lg * 4 + r;
          int tok = t0 - HALO + row;
          float v = acc[m][nf][r] + bv[nf];
          if (RELU) v = fmaxf(v, 0.f);
          if (tok < 0 || tok >= T) v = 0.f;   // reference zero-pads every conv at sequence edges
          act[row * APITCH + o] = f2b(v);
        }
      }
  }
  asm volatile("s_waitcnt lgkmcnt(0)" ::: "memory");
  __builtin_amdgcn_s_barrier();          // E2: writes visible
}

// ---- fully fused block kernel, 1 block/CU, weights streamed L2->LDS once per block ----
__global__ __launch_bounds__(256, 1) void k_fused(
    const char* __restrict__ xtp, const char* __restrict__ wtp,
    const float* __restrict__ eb1, const float* __restrict__ eb2,
    const float* __restrict__ db1, const float* __restrict__ db2, const float* __restrict__ db3,
    const char* __restrict__ embp, const float* __restrict__ e2,
    int* __restrict__ hist, double* __restrict__ dsum,
    float* __restrict__ xhat, int T) {
  __shared__ __align__(16) u16 act[16896];        // 33,792 B (82 rows x 400B + 1KB-granule pad)
  __shared__ __align__(16) u16 wb[3][18432];      // 3 x 36,864 B chunk ring
  __shared__ int hs[NCODES];
  __shared__ float wsum[4];
  const int tid = threadIdx.x;
  const int wv = tid >> 6, lane = tid & 63, lr = lane & 15, lg = lane >> 4;
  const int bid = blockIdx.x;
  const int b = bid >> 7, tile = bid & 127;
  const int t0 = tile * 64;
  const bool edge = (tile == 0) || (tile == 127);
  const int oB = wv * 48;
  if (tid < NCODES) hs[tid] = 0;

  // biases first: oldest vmcnt entries, drained by the first counted wait
  float bvv[5][3];
  #pragma unroll
  for (int nf = 0; nf < 3; ++nf) {
    int o = oB + nf * 16 + lr;
    bvv[0][nf] = eb1[o]; bvv[1][nf] = eb2[o];
    bvv[2][nf] = db1[o]; bvv[3][nf] = db2[o]; bvv[4][nf] = db3[o];
  }

  // stage x tile (33 x 1KB chunks, padded source -> always in-bounds, pads are zeros)
  {
    const char* src = xtp + (size_t)(b * RPB + LEAD + t0 - HALO) * 400;
    for (int c = wv; c < 33; c += 4)
      gld16(src + c * 1024 + lane * 16, (char*)act + c * 1024);
  }
  // prologue: weight chunk 0 only (chunk 1 issued by step 0)
  {
    const char* s0 = wtp + (size_t)(wv * 9) * 1024 + lane * 16;
    char* d0 = (char*)wb[0] + (wv * 9) * 1024;
    #pragma unroll
    for (int j = 0; j < 9; ++j) gld16(s0 + j * 1024, d0 + j * 1024);
  }

  stage<0, 5, 1, true,  true >(wtp, act, wb, bvv[0], oB, wv, lane, lr, lg, t0, T, edge);  // h1
  stage<6, 5, 1, false, false>(wtp, act, wb, bvv[1], oB, wv, lane, lr, lg, t0, T, edge);  // z_e (drains vmcnt)

  // ---- VQ: emb via LDS (2 x 25.6KB halves into wb[0]/wb[1]), z_e rows from act ----
  {
    #pragma unroll
    for (int j = 0; j < 7; ++j) {
      int c = wv + 4 * j;                 // 28 chunks (3 pad chunks read slack, never consumed)
      gld16(embp + c * 1024 + lane * 16, (char*)wb[0] + c * 1024);
    }
    #pragma unroll
    for (int j = 0; j < 7; ++j) {
      int c = wv + 4 * j;
      gld16(embp + 25600 + c * 1024 + lane * 16, (char*)wb[1] + c * 1024);
    }
    asm volatile("s_waitcnt vmcnt(0)" ::: "memory");
    __builtin_amdgcn_sched_barrier(0);
    __builtin_amdgcn_s_barrier();

    const int row = HALO + wv * 16 + lr;
    f32x4 va[8];
    #pragma unroll
    for (int n = 0; n < 8; ++n) va[n] = f32x4{0.f, 0.f, 0.f, 0.f};
    #pragma unroll
    for (int cb = 0; cb < 6; ++cb) {
      s16x8 az = *(const s16x8*)(act + row * APITCH + cb * 32 + lg * 8);
      #pragma unroll
      for (int n = 0; n < 4; ++n) {
        s16x8 e1f = *(const s16x8*)(wb[0] + (n * 16 + lr) * APITCH + cb * 32 + lg * 8);
        va[n] = __builtin_amdgcn_mfma_f32_16x16x32_bf16(az, e1f, va[n], 0, 0, 0);
        s16x8 e2f = *(const s16x8*)(wb[1] + (n * 16 + lr) * APITCH + cb * 32 + lg * 8);
        va[n + 4] = __builtin_amdgcn_mfma_f32_16x16x32_bf16(az, e2f, va[n + 4], 0, 0, 0);
      }
    }
    float z2 = 0.f;
    const u16* zr = act + row * APITCH + lg * 48;
    #pragma unroll
    for (int j = 0; j < 48; j += 8) {
      s16x8 vv = *(const s16x8*)(zr + j);
      #pragma unroll
      for (int e = 0; e < 8; ++e) { float f = b2f((u16)vv[e]); z2 += f * f; }
    }
    z2 += __shfl_xor(z2, 16, 64);
    z2 += __shfl_xor(z2, 32, 64);
    float smin[4]; int imin[4];
    #pragma unroll
    for (int r = 0; r < 4; ++r) { smin[r] = 3.4e38f; imin[r] = 0; }
    #pragma unroll
    for (int n = 0; n < 8; ++n) {
      int code = n * 16 + lr;
      float ev = e2[code];
      #pragma unroll
      for (int r = 0; r < 4; ++r) {
        float sc = ev - 2.f * va[n][r];
        if (sc < smin[r]) { smin[r] = sc; imin[r] = code; }
      }
    }
    #pragma unroll
    for (int m = 1; m < 16; m <<= 1) {
      #pragma unroll
      for (int r = 0; r < 4; ++r) {
        float so = __shfl_xor(smin[r], m, 64);
        int io = __shfl_xor(imin[r], m, 64);
        if (so < smin[r] || (so == smin[r] && io < imin[r])) { smin[r] = so; imin[r] = io; }
      }
    }
    float z2t[4];
    #pragma unroll
    for (int r = 0; r < 4; ++r) z2t[r] = __shfl(z2, lg * 4 + r, 64);
    float dpart = 0.f;
    if (lr == 0) {
      #pragma unroll
      for (int r = 0; r < 4; ++r) {
        dpart += z2t[r] + smin[r];
        atomicAdd(&hs[imin[r]], 1);
      }
    }
    #pragma unroll
    for (int m = 1; m < 64; m <<= 1) dpart += __shfl_xor(dpart, m, 64);
    if (lane == 0) wsum[wv] = dpart;
    asm volatile("s_waitcnt lgkmcnt(0)" ::: "memory");
    __builtin_amdgcn_s_barrier();         // C: all VQ LDS reads/writes done
    // issue dec1 chunk 12 (wb[0]; its readers all finished before C)
    {
      const char* s = wtp + (size_t)12 * WCH + (wv * 9) * 1024 + lane * 16;
      char* d = (char*)wb[0] + (wv * 9) * 1024;
      #pragma unroll
      for (int j = 0; j < 9; ++j) gld16(s + j * 1024, d + j * 1024);
    }
    if (tid == 0) {
      double tot = (double)wsum[0] + (double)wsum[1] + (double)wsum[2] + (double)wsum[3];
      atomicAdd(dsum, tot);
    }
    if (tid < NCODES && hs[tid] > 0) atomicAdd(&hist[tid], hs[tid]);
  }

  stage<12, 5, 1, true, true>(wtp, act, wb, bvv[2], oB, wv, lane, lr, lg, t0, T, edge);  // dec1
  stage<18, 5, 1, true, true>(wtp, act, wb, bvv[3], oB, wv, lane, lr, lg, t0, T, edge);  // dec2

  // ---- dec3 (chunks 24..29), acc kept in regs ----
  f32x4 acc5[4][3];
  #pragma unroll
  for (int m = 0; m < 4; ++m)
    #pragma unroll
    for (int n = 0; n < 3; ++n) acc5[m][n] = f32x4{0.f, 0.f, 0.f, 0.f};
  {
    const u16* arow = act + lr * APITCH + lg * 8;   // FIX: + lr*APITCH (r9 bug)
    #pragma unroll
    for (int cb = 0; cb < 6; ++cb) {
      const int g = 24 + cb;
      if (cb < 5) {
        const char* src = wtp + (size_t)(g + 1) * WCH + (wv * 9) * 1024 + lane * 16;
        char* dst = (char*)wb[(g + 1) % 3] + (wv * 9) * 1024;
        #pragma unroll
        for (int j = 0; j < 9; ++j) gld16(src + j * 1024, dst + j * 1024);
        asm volatile("s_waitcnt vmcnt(9)" ::: "memory");
      } else {
        asm volatile("s_waitcnt vmcnt(0)" ::: "memory");
      }
      __builtin_amdgcn_sched_barrier(0);
      __builtin_amdgcn_s_barrier();
      const u16* wq = wb[g % 3];
      #pragma unroll
      for (int k = 0; k < 3; ++k) {
        s16x8 af[4];
        #pragma unroll
        for (int m = 0; m < 4; ++m)
          af[m] = *(const s16x8*)(arow + (8 + 16 * m + k) * APITCH + cb * 32);
        #pragma unroll
        for (int nf = 0; nf < 3; ++nf) {
          s16x8 wf = *(const s16x8*)(wq + (k * CCH + oB + nf * 16 + lr) * 32 + lg * 8);
          #pragma unroll
          for (int m = 0; m < 4; ++m)
            acc5[m][nf] = __builtin_amdgcn_mfma_f32_16x16x32_bf16(af[m], wf, acc5[m][nf], 0, 0, 0);
        }
      }
    }
  }

  // ---- f32 (B,C,T) output via 2-pass LDS transpose (96 ch per pass) ----
  float* ft = (float*)act;
  float* dstb = xhat + (size_t)b * CCH * T + t0;
  #pragma unroll
  for (int p = 0; p < 2; ++p) {
    __builtin_amdgcn_s_barrier();        // p0: act reads done; p1: pass-0 ft reads consumed
    if ((wv >> 1) == p) {
      #pragma unroll
      for (int m = 0; m < 4; ++m)
        #pragma unroll
        for (int nf = 0; nf < 3; ++nf) {
          int o = oB + nf * 16 + lr - p * 96;
          #pragma unroll
          for (int r = 0; r < 4; ++r) {
            int tl = 16 * m + lg * 4 + r;
            ft[o * 66 + tl] = acc5[m][nf][r] + bvv[4][nf];
          }
        }
    }
    asm volatile("s_waitcnt lgkmcnt(0)" ::: "memory");
    __builtin_amdgcn_s_barrier();
    for (int s = tid; s < 96 * 64; s += 256) {
      int o = s >> 6, tl = s & 63;
      dstb[(size_t)(o + p * 96) * T + tl] = ft[o * 66 + tl];
    }
  }
}

__global__ __launch_bounds__(128) void k_fin(const int* __restrict__ hist,
                                             const double* __restrict__ dsum,
                                             float* __restrict__ out, int N, int ppos) {
  __shared__ float H[NCODES];
  int t = threadIdx.x;
  float p = (float)hist[t] / (float)N;
  H[t] = p * logf(p + 1e-10f);
  __syncthreads();
  if (t == 0) {
    float s = 0.f;
    for (int i = 0; i < NCODES; ++i) s += H[i];
    out[ppos] = expf(-s);
    out[0] = (float)(1.25 * (*dsum) / ((double)N * (double)CCH));
  }
}

extern "C" void kernel_launch(void* const* d_in, const int* in_sizes, int n_in,
                              void* d_out, int out_size, void* d_ws, size_t ws_size,
                              hipStream_t stream) {
  const int B = 16, T = 8192, N = B * T;
  const float* x   = (const float*)d_in[0];
  const float* ew1 = (const float*)d_in[1];
  const float* eb1 = (const float*)d_in[2];
  const float* ew2 = (const float*)d_in[3];
  const float* eb2 = (const float*)d_in[4];
  const float* emb = (const float*)d_in[5];
  const float* dw1 = (const float*)d_in[6];
  const float* db1 = (const float*)d_in[7];
  const float* dw2 = (const float*)d_in[8];
  const float* db2 = (const float*)d_in[9];
  const float* dw3 = (const float*)d_in[10];
  const float* db3 = (const float*)d_in[11];

  char* ws = (char*)d_ws;
  char*  xtp  = ws;                          // 16*8216 rows * 400 B = 52,582,400 (+pad)
  char*  wtp  = ws + 52583424;               // 30 chunks * 36,864 = 1,105,920
  char*  embp = ws + 53689344;               // 128*400 = 51,200 (+4 KB read slack)
  float* e2   = (float*)(ws + 53744640);
  int*   hist = (int*)(ws + 53745152);
  double* dsum = (double*)(ws + 53745664);

  const int wblocks = (3 * CCH * CCH + 255) / 256;          // 432
  k_wconv<<<wblocks, 256, 0, stream>>>(ew1, (u16*)wtp);
  k_wconv<<<wblocks, 256, 0, stream>>>(ew2, (u16*)wtp + 110592);
  k_wconv<<<wblocks, 256, 0, stream>>>(dw1, (u16*)wtp + 2 * 110592);
  k_wconv<<<wblocks, 256, 0, stream>>>(dw2, (u16*)wtp + 3 * 110592);
  k_wconv<<<wblocks, 256, 0, stream>>>(dw3, (u16*)wtp + 4 * 110592);
  k_emb<<<NCODES, 64, 0, stream>>>(emb, (u16*)embp, e2);
  k_zero<<<1, 256, 0, stream>>>(hist, dsum);
  k_padz<<<B, 256, 0, stream>>>((u16*)xtp);
  k_tin<<<B * 6 * (T / 32), 256, 0, stream>>>(x, (u16*)xtp, B, T);

  k_fused<<<B * (T / 64), 256, 0, stream>>>(xtp, wtp, eb1, eb2, db1, db2, db3,
                                            embp, e2, hist, dsum, (float*)d_out + 1, T);
  k_fin<<<1, 128, 0, stream>>>(hist, dsum, (float*)d_out, N, out_size - 1);
}

// Round 11
// 286.571 us; speedup vs baseline: 1.2728x; 1.1857x over previous
//
#include <hip/hip_runtime.h>
#include <hip/hip_bf16.h>
#include <stdint.h>

typedef short s16x8 __attribute__((ext_vector_type(8)));
typedef float f32x4 __attribute__((ext_vector_type(4)));
typedef unsigned int u32;
typedef unsigned short u16;

#define CCH 192
#define APITCH 200     // u16 pitch of act rows (400 B)
#define NCODES 128
#define HALO 9
#define RPB 8216       // padded rows per batch in xtp: 12 lead + 8192 + 12 trail
#define LEAD 12
#define TOK 128        // tokens per block
#define AROWS 146      // staged rows: t0-9 .. t0+136
#define WSTRIDE 40960  // padded weight chunk stride (36,864 valid + pad): 40 x 1KB granules
#define WCHV 36864

__device__ __forceinline__ u16 f2b(float f) {
  u32 u = __builtin_bit_cast(u32, f);
  u = (u + 0x7fffu + ((u >> 16) & 1u)) >> 16;   // RNE
  return (u16)u;
}
__device__ __forceinline__ float b2f(u16 h) {
  return __builtin_bit_cast(float, ((u32)h) << 16);
}
__device__ __forceinline__ void gld16(const void* g, void* l) {
  __builtin_amdgcn_global_load_lds(
      (const __attribute__((address_space(1))) void*)g,
      (__attribute__((address_space(3))) void*)l, 16, 0, 0);
}

// ---- x (B,C,T) f32 -> xtp (padded rows, pitch 200) bf16 ----
__global__ __launch_bounds__(256) void k_tin(const float* __restrict__ x, u16* __restrict__ xtp,
                                             int B, int T) {
  __shared__ float tile[32][36];
  int nt = T >> 5;
  int bid = blockIdx.x;
  int b = bid / (6 * nt);
  int rem = bid % (6 * nt);
  int cb = rem / nt, tb = rem % nt;
  int tid = threadIdx.x;
  {
    int c = tid >> 3, seg = tid & 7;
    const float* src = x + ((size_t)b * CCH + cb * 32 + c) * T + tb * 32 + seg * 4;
    float4 v = *(const float4*)src;
    tile[c][seg * 4 + 0] = v.x; tile[c][seg * 4 + 1] = v.y;
    tile[c][seg * 4 + 2] = v.z; tile[c][seg * 4 + 3] = v.w;
  }
  __syncthreads();
  {
    int t = tid >> 3, cs = tid & 7;
    u16* dst = xtp + ((size_t)(b * RPB + LEAD + tb * 32 + t)) * APITCH + cb * 32 + cs * 4;
    ushort4 o;
    o.x = f2b(tile[cs * 4 + 0][t]); o.y = f2b(tile[cs * 4 + 1][t]);
    o.z = f2b(tile[cs * 4 + 2][t]); o.w = f2b(tile[cs * 4 + 3][t]);
    *(ushort4*)dst = o;
  }
}

// ---- zero the pad rows of xtp (12 lead + 12 trail per batch) ----
__global__ __launch_bounds__(256) void k_padz(u16* __restrict__ xtp) {
  int b = blockIdx.x;
  for (int i = threadIdx.x; i < 24 * 25; i += 256) {
    int r = i / 25, c = i - (i / 25) * 25;
    int row = (r < 12) ? r : (RPB - 12 + (r - 12));
    uint4 z = {0u, 0u, 0u, 0u};
    *(uint4*)((char*)xtp + ((size_t)(b * RPB + row)) * 400 + c * 16) = z;
  }
}

// ---- weights (O,I,3) f32 -> chunked bf16, chunk cb at u16 index cb*20480, layout [k][o][i32] ----
__global__ __launch_bounds__(256) void k_wconv(const float* __restrict__ w, u16* __restrict__ dst) {
  int i = blockIdx.x * 256 + threadIdx.x;
  if (i >= 3 * CCH * CCH) return;
  int cb = i / 18432;
  int r = i - cb * 18432;
  int k = r / 6144;
  int r2 = r - k * 6144;
  int o = r2 / 32, il = r2 - o * 32;
  dst[cb * 20480 + k * 6144 + o * 32 + il] = f2b(w[(o * CCH + cb * 32 + il) * 3 + k]);
}

// ---- emb (K,C) f32 -> embp bf16 pitch 200 + ||e||^2 f32 ----
__global__ __launch_bounds__(64) void k_emb(const float* __restrict__ emb, u16* __restrict__ embp,
                                            float* __restrict__ e2) {
  int code = blockIdx.x, lane = threadIdx.x;
  float s = 0.f;
  for (int j = lane * 3; j < lane * 3 + 3; ++j) {
    float v = emb[code * CCH + j];
    embp[code * APITCH + j] = f2b(v);
    s += v * v;
  }
  if (lane < 8) embp[code * APITCH + 192 + lane] = 0;
  #pragma unroll
  for (int m = 1; m < 64; m <<= 1) s += __shfl_xor(s, m, 64);
  if (lane == 0) e2[code] = s;
}

__global__ void k_zero(int* hist, double* dsum) {
  int t = threadIdx.x;
  if (t < NCODES) hist[t] = 0;
  if (t == 0) *dsum = 0.0;
}

// ---- one conv stage, 8 waves (2M x 4N), in-place, 2-ring streamed weights ----
// per step: vmcnt(0) [own loads done] -> barrier -> issue chunk g+1 -> compute chunk g.
// Issue-after-barrier makes the 2-deep ring race-free (target buffer last read 1 step ago,
// all waves past barrier => done). M-halves overlap rows 65-80 with identical values (benign).
template<int G0, bool RELU, bool ISSUE_NEXT>
__device__ __forceinline__ void stage(const char* __restrict__ wtp, u16* __restrict__ act,
                                      u16 (*wb)[20480], const float* bv,
                                      int oB, const u16* arow, int rbase,
                                      int wv, int lane, int lr, int lg,
                                      int t0, int T, bool edge) {
  f32x4 acc[5][3];
  #pragma unroll
  for (int m = 0; m < 5; ++m)
    #pragma unroll
    for (int n = 0; n < 3; ++n) acc[m][n] = f32x4{0.f, 0.f, 0.f, 0.f};
  #pragma unroll
  for (int cb = 0; cb < 6; ++cb) {
    const int g = G0 + cb;
    asm volatile("s_waitcnt vmcnt(0)" ::: "memory");    // own chunk-g granules (+older) done
    __builtin_amdgcn_sched_barrier(0);
    __builtin_amdgcn_s_barrier();                       // all waves' granules visible; prev reads done
    if (cb < 5 || ISSUE_NEXT) {
      const char* src = wtp + (size_t)(g + 1) * WSTRIDE + (wv * 5) * 1024 + lane * 16;
      char* dst = (char*)wb[(g + 1) & 1] + (wv * 5) * 1024;
      #pragma unroll
      for (int j = 0; j < 5; ++j) gld16(src + j * 1024, dst + j * 1024);
    }
    const u16* wq = wb[g & 1];
    #pragma unroll
    for (int k = 0; k < 3; ++k) {
      s16x8 af[5];
      #pragma unroll
      for (int m = 0; m < 5; ++m)
        af[m] = *(const s16x8*)(arow + (16 * m + k) * APITCH + cb * 32);
      #pragma unroll
      for (int nf = 0; nf < 3; ++nf) {
        s16x8 wf = *(const s16x8*)(wq + (k * CCH + oB + nf * 16 + lr) * 32 + lg * 8);
        #pragma unroll
        for (int m = 0; m < 5; ++m)
          acc[m][nf] = __builtin_amdgcn_mfma_f32_16x16x32_bf16(af[m], wf, acc[m][nf], 0, 0, 0);
      }
    }
  }
  __builtin_amdgcn_s_barrier();          // E1: all waves done reading act
  if (!edge) {
    #pragma unroll
    for (int m = 0; m < 5; ++m)
      #pragma unroll
      for (int nf = 0; nf < 3; ++nf) {
        int o = oB + nf * 16 + lr;
        #pragma unroll
        for (int r = 0; r < 4; ++r) {
          int row = rbase + 16 * m + lg * 4 + r;
          float v = acc[m][nf][r] + bv[nf];
          if (RELU) v = fmaxf(v, 0.f);
          act[row * APITCH + o] = f2b(v);
        }
      }
  } else {
    #pragma unroll
    for (int m = 0; m < 5; ++m)
      #pragma unroll
      for (int nf = 0; nf < 3; ++nf) {
        int o = oB + nf * 16 + lr;
        #pragma unroll
        for (int r = 0; r < 4; ++r) {
          int row = rbase + 16 * m + lg * 4 + r;
          int tok = t0 - HALO + row;
          float v = acc[m][nf][r] + bv[nf];
          if (RELU) v = fmaxf(v, 0.f);
          if (tok < 0 || tok >= T) v = 0.f;   // reference zero-pads every conv at sequence edges
          act[row * APITCH + o] = f2b(v);
        }
      }
  }
  asm volatile("s_waitcnt lgkmcnt(0)" ::: "memory");
  __builtin_amdgcn_s_barrier();          // E2: writes visible
}

// ---- fully fused, 512 threads (8 waves = 2/SIMD), 128 tokens/block, 1 block/CU ----
__global__ __launch_bounds__(512, 1) void k_fused(
    const char* __restrict__ xtp, const char* __restrict__ wtp,
    const float* __restrict__ eb1, const float* __restrict__ eb2,
    const float* __restrict__ db1, const float* __restrict__ db2, const float* __restrict__ db3,
    const char* __restrict__ embp, const float* __restrict__ e2,
    int* __restrict__ hist, double* __restrict__ dsum,
    float* __restrict__ xhat, int T) {
  __shared__ __align__(16) u16 act[AROWS * APITCH];   // 58,400 B
  __shared__ __align__(16) u16 wb[2][20480];          // 2 x 40,960 B ring
  __shared__ int hs[NCODES];
  __shared__ float wsum[8];
  const int tid = threadIdx.x;
  const int wv = tid >> 6, lane = tid & 63, lr = lane & 15, lg = lane >> 4;
  const int nw = wv & 3, mw = wv >> 2;
  const int bid = blockIdx.x;
  const int b = bid >> 6, tile = bid & 63;            // T/128 = 64 tiles per batch
  const int t0 = tile * TOK;
  const bool edge = (tile == 0) || (tile == 63);
  const int oB = nw * 48;
  const int rbase = 1 + mw * 64;                      // stage output rows [rbase, rbase+80)
  const u16* arow = act + (rbase - 1 + lr) * APITCH + lg * 8;
  if (tid < NCODES) hs[tid] = 0;

  float bvv[5][3];
  #pragma unroll
  for (int nf = 0; nf < 3; ++nf) {
    int o = oB + nf * 16 + lr;
    bvv[0][nf] = eb1[o]; bvv[1][nf] = eb2[o];
    bvv[2][nf] = db1[o]; bvv[3][nf] = db2[o]; bvv[4][nf] = db3[o];
  }

  // stage x rows t0-9 .. t0+136 (146 x 400B = 3650 x 16B granules)
  {
    const char* src = xtp + (size_t)(b * RPB + LEAD + t0 - HALO) * 400;
    #pragma unroll
    for (int s = 0; s < 8; ++s) {
      int c = tid + s * 512;
      if (c < AROWS * 25)
        gld16(src + (size_t)c * 16, (char*)act + (size_t)c * 16);
    }
  }
  // prologue: weight chunk 0 (chunk 1 issued inside step 0)
  {
    const char* s0 = wtp + (size_t)(wv * 5) * 1024 + lane * 16;
    char* d0 = (char*)wb[0] + (wv * 5) * 1024;
    #pragma unroll
    for (int j = 0; j < 5; ++j) gld16(s0 + j * 1024, d0 + j * 1024);
  }

  stage<0,  true,  true >(wtp, act, wb, bvv[0], oB, arow, rbase, wv, lane, lr, lg, t0, T, edge); // h1
  stage<6,  false, false>(wtp, act, wb, bvv[1], oB, arow, rbase, wv, lane, lr, lg, t0, T, edge); // z_e

  // ---- VQ on LDS z_e; 8 waves x 16 tokens; emb (2 x 25 granules) into wb[0]/wb[1] ----
  {
    #pragma unroll
    for (int j = 0; j < 4; ++j) {
      int c = wv + 8 * j;
      if (c < 25) {
        gld16(embp + c * 1024 + lane * 16, (char*)wb[0] + c * 1024);
        gld16(embp + 25600 + c * 1024 + lane * 16, (char*)wb[1] + c * 1024);
      }
    }
    asm volatile("s_waitcnt vmcnt(0)" ::: "memory");
    __builtin_amdgcn_sched_barrier(0);
    __builtin_amdgcn_s_barrier();

    const int row = HALO + wv * 16 + lr;
    f32x4 va[8];
    #pragma unroll
    for (int n = 0; n < 8; ++n) va[n] = f32x4{0.f, 0.f, 0.f, 0.f};
    #pragma unroll
    for (int cb = 0; cb < 6; ++cb) {
      s16x8 az = *(const s16x8*)(act + row * APITCH + cb * 32 + lg * 8);
      #pragma unroll
      for (int n = 0; n < 4; ++n) {
        s16x8 e1f = *(const s16x8*)(wb[0] + (n * 16 + lr) * APITCH + cb * 32 + lg * 8);
        va[n] = __builtin_amdgcn_mfma_f32_16x16x32_bf16(az, e1f, va[n], 0, 0, 0);
        s16x8 e2f = *(const s16x8*)(wb[1] + (n * 16 + lr) * APITCH + cb * 32 + lg * 8);
        va[n + 4] = __builtin_amdgcn_mfma_f32_16x16x32_bf16(az, e2f, va[n + 4], 0, 0, 0);
      }
    }
    float z2 = 0.f;
    const u16* zr = act + row * APITCH + lg * 48;
    #pragma unroll
    for (int j = 0; j < 48; j += 8) {
      s16x8 vv = *(const s16x8*)(zr + j);
      #pragma unroll
      for (int e = 0; e < 8; ++e) { float f = b2f((u16)vv[e]); z2 += f * f; }
    }
    z2 += __shfl_xor(z2, 16, 64);
    z2 += __shfl_xor(z2, 32, 64);
    float smin[4]; int imin[4];
    #pragma unroll
    for (int r = 0; r < 4; ++r) { smin[r] = 3.4e38f; imin[r] = 0; }
    #pragma unroll
    for (int n = 0; n < 8; ++n) {
      int code = n * 16 + lr;
      float ev = e2[code];
      #pragma unroll
      for (int r = 0; r < 4; ++r) {
        float sc = ev - 2.f * va[n][r];
        if (sc < smin[r]) { smin[r] = sc; imin[r] = code; }
      }
    }
    #pragma unroll
    for (int m = 1; m < 16; m <<= 1) {
      #pragma unroll
      for (int r = 0; r < 4; ++r) {
        float so = __shfl_xor(smin[r], m, 64);
        int io = __shfl_xor(imin[r], m, 64);
        if (so < smin[r] || (so == smin[r] && io < imin[r])) { smin[r] = so; imin[r] = io; }
      }
    }
    float z2t[4];
    #pragma unroll
    for (int r = 0; r < 4; ++r) z2t[r] = __shfl(z2, lg * 4 + r, 64);
    float dpart = 0.f;
    if (lr == 0) {
      #pragma unroll
      for (int r = 0; r < 4; ++r) {
        dpart += z2t[r] + smin[r];
        atomicAdd(&hs[imin[r]], 1);
      }
    }
    #pragma unroll
    for (int m = 1; m < 64; m <<= 1) dpart += __shfl_xor(dpart, m, 64);
    if (lane == 0) wsum[wv] = dpart;
    asm volatile("s_waitcnt lgkmcnt(0)" ::: "memory");
    __builtin_amdgcn_s_barrier();         // C: all VQ LDS traffic done
    // issue dec1 chunk 12 -> wb[0]
    {
      const char* s = wtp + (size_t)12 * WSTRIDE + (wv * 5) * 1024 + lane * 16;
      char* d = (char*)wb[0] + (wv * 5) * 1024;
      #pragma unroll
      for (int j = 0; j < 5; ++j) gld16(s + j * 1024, d + j * 1024);
    }
    if (tid == 0) {
      double tot = 0.0;
      #pragma unroll
      for (int w = 0; w < 8; ++w) tot += (double)wsum[w];
      atomicAdd(dsum, tot);
    }
    if (tid < NCODES && hs[tid] > 0) atomicAdd(&hist[tid], hs[tid]);
  }

  stage<12, true, true>(wtp, act, wb, bvv[2], oB, arow, rbase, wv, lane, lr, lg, t0, T, edge);  // dec1
  stage<18, true, true>(wtp, act, wb, bvv[3], oB, arow, rbase, wv, lane, lr, lg, t0, T, edge);  // dec2

  // ---- dec3 (chunks 24..29): own 64 rows per M-half, acc in regs ----
  f32x4 acc5[4][3];
  #pragma unroll
  for (int m = 0; m < 4; ++m)
    #pragma unroll
    for (int n = 0; n < 3; ++n) acc5[m][n] = f32x4{0.f, 0.f, 0.f, 0.f};
  {
    const u16* arow3 = act + (8 + mw * 64 + lr) * APITCH + lg * 8;
    #pragma unroll
    for (int cb = 0; cb < 6; ++cb) {
      const int g = 24 + cb;
      asm volatile("s_waitcnt vmcnt(0)" ::: "memory");
      __builtin_amdgcn_sched_barrier(0);
      __builtin_amdgcn_s_barrier();
      if (cb < 5) {
        const char* src = wtp + (size_t)(g + 1) * WSTRIDE + (wv * 5) * 1024 + lane * 16;
        char* dst = (char*)wb[(g + 1) & 1] + (wv * 5) * 1024;
        #pragma unroll
        for (int j = 0; j < 5; ++j) gld16(src + j * 1024, dst + j * 1024);
      }
      const u16* wq = wb[g & 1];
      #pragma unroll
      for (int k = 0; k < 3; ++k) {
        s16x8 af[4];
        #pragma unroll
        for (int m = 0; m < 4; ++m)
          af[m] = *(const s16x8*)(arow3 + (16 * m + k) * APITCH + cb * 32);
        #pragma unroll
        for (int nf = 0; nf < 3; ++nf) {
          s16x8 wf = *(const s16x8*)(wq + (k * CCH + oB + nf * 16 + lr) * 32 + lg * 8);
          #pragma unroll
          for (int m = 0; m < 4; ++m)
            acc5[m][nf] = __builtin_amdgcn_mfma_f32_16x16x32_bf16(af[m], wf, acc5[m][nf], 0, 0, 0);
        }
      }
    }
  }

  // ---- f32 (B,C,T) output via 2-pass LDS transpose (96 ch x 128 tok per pass) ----
  float* ft = (float*)act;                 // 96*130*4 = 49,920 B <= act
  float* dstb = xhat + (size_t)b * CCH * T + t0;
  #pragma unroll
  for (int p = 0; p < 2; ++p) {
    __builtin_amdgcn_s_barrier();          // p0: act reads done; p1: pass-0 stores consumed
    if ((nw >> 1) == p) {
      #pragma unroll
      for (int m = 0; m < 4; ++m)
        #pragma unroll
        for (int nf = 0; nf < 3; ++nf) {
          int o = (nw & 1) * 48 + nf * 16 + lr;
          #pragma unroll
          for (int r = 0; r < 4; ++r) {
            int tl = mw * 64 + 16 * m + lg * 4 + r;
            ft[o * 130 + tl] = acc5[m][nf][r] + bvv[4][nf];
          }
        }
    }
    asm volatile("s_waitcnt lgkmcnt(0)" ::: "memory");
    __builtin_amdgcn_s_barrier();
    #pragma unroll
    for (int i = 0; i < 24; ++i) {
      int s = tid + i * 512;
      int o = s >> 7, tl = s & 127;
      dstb[(size_t)(o + p * 96) * T + tl] = ft[o * 130 + tl];
    }
  }
}

__global__ __launch_bounds__(128) void k_fin(const int* __restrict__ hist,
                                             const double* __restrict__ dsum,
                                             float* __restrict__ out, int N, int ppos) {
  __shared__ float H[NCODES];
  int t = threadIdx.x;
  float p = (float)hist[t] / (float)N;
  H[t] = p * logf(p + 1e-10f);
  __syncthreads();
  if (t == 0) {
    float s = 0.f;
    for (int i = 0; i < NCODES; ++i) s += H[i];
    out[ppos] = expf(-s);
    out[0] = (float)(1.25 * (*dsum) / ((double)N * (double)CCH));
  }
}

extern "C" void kernel_launch(void* const* d_in, const int* in_sizes, int n_in,
                              void* d_out, int out_size, void* d_ws, size_t ws_size,
                              hipStream_t stream) {
  const int B = 16, T = 8192, N = B * T;
  const float* x   = (const float*)d_in[0];
  const float* ew1 = (const float*)d_in[1];
  const float* eb1 = (const float*)d_in[2];
  const float* ew2 = (const float*)d_in[3];
  const float* eb2 = (const float*)d_in[4];
  const float* emb = (const float*)d_in[5];
  const float* dw1 = (const float*)d_in[6];
  const float* db1 = (const float*)d_in[7];
  const float* dw2 = (const float*)d_in[8];
  const float* db2 = (const float*)d_in[9];
  const float* dw3 = (const float*)d_in[10];
  const float* db3 = (const float*)d_in[11];

  char* ws = (char*)d_ws;
  char*  xtp  = ws;                          // 16*8216*400 = 52,582,400
  char*  wtp  = ws + 52582400;               // 30 chunks * 40,960 = 1,228,800
  char*  embp = ws + 53811200;               // 51,200 valid + slack
  float* e2   = (float*)(ws + 53876736);
  int*   hist = (int*)(ws + 53877248);
  double* dsum = (double*)(ws + 53877760);

  const int wblocks = (3 * CCH * CCH + 255) / 256;          // 432
  k_wconv<<<wblocks, 256, 0, stream>>>(ew1, (u16*)wtp);
  k_wconv<<<wblocks, 256, 0, stream>>>(ew2, (u16*)wtp + 6 * 20480);
  k_wconv<<<wblocks, 256, 0, stream>>>(dw1, (u16*)wtp + 12 * 20480);
  k_wconv<<<wblocks, 256, 0, stream>>>(dw2, (u16*)wtp + 18 * 20480);
  k_wconv<<<wblocks, 256, 0, stream>>>(dw3, (u16*)wtp + 24 * 20480);
  k_emb<<<NCODES, 64, 0, stream>>>(emb, (u16*)embp, e2);
  k_zero<<<1, 256, 0, stream>>>(hist, dsum);
  k_padz<<<B, 256, 0, stream>>>((u16*)xtp);
  k_tin<<<B * 6 * (T / 32), 256, 0, stream>>>(x, (u16*)xtp, B, T);

  k_fused<<<B * (T / TOK), 512, 0, stream>>>(xtp, wtp, eb1, eb2, db1, db2, db3,
                                             embp, e2, hist, dsum, (float*)d_out + 1, T);
  k_fin<<<1, 128, 0, stream>>>(hist, dsum, (float*)d_out, N, out_size - 1);
}

// Round 12
// 280.295 us; speedup vs baseline: 1.3013x; 1.0224x over previous
//
#include <hip/hip_runtime.h>
#include <hip/hip_bf16.h>
#include <stdint.h>

typedef short s16x8 __attribute__((ext_vector_type(8)));
typedef float f32x4 __attribute__((ext_vector_type(4)));
typedef unsigned int u32;
typedef unsigned short u16;

#define CCH 192
#define APITCH 200     // u16 pitch of act rows (400 B)
#define NCODES 128
#define HALO 9
#define RPB 8216       // padded rows per batch in xtp: 12 lead + 8192 + 12 trail
#define LEAD 12
#define TOK 128        // tokens per block
#define AROWS 146      // staged rows: t0-9 .. t0+136
#define WSTRIDE 40960  // padded weight chunk stride (36,864 valid + pad): 40 x 1KB granules

__device__ __forceinline__ u16 f2b(float f) {
  u32 u = __builtin_bit_cast(u32, f);
  u = (u + 0x7fffu + ((u >> 16) & 1u)) >> 16;   // RNE
  return (u16)u;
}
__device__ __forceinline__ float b2f(u16 h) {
  return __builtin_bit_cast(float, ((u32)h) << 16);
}
__device__ __forceinline__ void gld16(const void* g, void* l) {
  __builtin_amdgcn_global_load_lds(
      (const __attribute__((address_space(1))) void*)g,
      (__attribute__((address_space(3))) void*)l, 16, 0, 0);
}

// ---- x (B,C,T) f32 -> xtp (padded rows, pitch 200) bf16 ----
__global__ __launch_bounds__(256) void k_tin(const float* __restrict__ x, u16* __restrict__ xtp,
                                             int B, int T) {
  __shared__ float tile[32][36];
  int nt = T >> 5;
  int bid = blockIdx.x;
  int b = bid / (6 * nt);
  int rem = bid % (6 * nt);
  int cb = rem / nt, tb = rem % nt;
  int tid = threadIdx.x;
  {
    int c = tid >> 3, seg = tid & 7;
    const float* src = x + ((size_t)b * CCH + cb * 32 + c) * T + tb * 32 + seg * 4;
    float4 v = *(const float4*)src;
    tile[c][seg * 4 + 0] = v.x; tile[c][seg * 4 + 1] = v.y;
    tile[c][seg * 4 + 2] = v.z; tile[c][seg * 4 + 3] = v.w;
  }
  __syncthreads();
  {
    int t = tid >> 3, cs = tid & 7;
    u16* dst = xtp + ((size_t)(b * RPB + LEAD + tb * 32 + t)) * APITCH + cb * 32 + cs * 4;
    ushort4 o;
    o.x = f2b(tile[cs * 4 + 0][t]); o.y = f2b(tile[cs * 4 + 1][t]);
    o.z = f2b(tile[cs * 4 + 2][t]); o.w = f2b(tile[cs * 4 + 3][t]);
    *(ushort4*)dst = o;
  }
}

// ---- zero the pad rows of xtp (12 lead + 12 trail per batch) ----
__global__ __launch_bounds__(256) void k_padz(u16* __restrict__ xtp) {
  int b = blockIdx.x;
  for (int i = threadIdx.x; i < 24 * 25; i += 256) {
    int r = i / 25, c = i - (i / 25) * 25;
    int row = (r < 12) ? r : (RPB - 12 + (r - 12));
    uint4 z = {0u, 0u, 0u, 0u};
    *(uint4*)((char*)xtp + ((size_t)(b * RPB + row)) * 400 + c * 16) = z;
  }
}

// ---- weights (O,I,3) f32 -> chunked bf16, chunk cb at u16 index cb*20480 ----
// Layout within chunk: [k][lg][o][8] (lg = i-halfgroup il>>3). Lane-varying read stride
// becomes 16B (o via lr) -> 2 lanes per 16B bank-slot per phase -> conflict-free ds_read_b128.
__global__ __launch_bounds__(256) void k_wconv(const float* __restrict__ w, u16* __restrict__ dst) {
  int i = blockIdx.x * 256 + threadIdx.x;
  if (i >= 3 * CCH * CCH) return;
  int cb = i / 18432;
  int r = i - cb * 18432;
  int k = r / 6144;
  int r2 = r - k * 6144;
  int o = r2 / 32, il = r2 - o * 32;
  dst[cb * 20480 + k * 6144 + (il >> 3) * 1536 + o * 8 + (il & 7)] =
      f2b(w[(o * CCH + cb * 32 + il) * 3 + k]);
}

// ---- emb (K,C) f32 -> embp bf16 pitch 200 + ||e||^2 f32 ----
__global__ __launch_bounds__(64) void k_emb(const float* __restrict__ emb, u16* __restrict__ embp,
                                            float* __restrict__ e2) {
  int code = blockIdx.x, lane = threadIdx.x;
  float s = 0.f;
  for (int j = lane * 3; j < lane * 3 + 3; ++j) {
    float v = emb[code * CCH + j];
    embp[code * APITCH + j] = f2b(v);
    s += v * v;
  }
  if (lane < 8) embp[code * APITCH + 192 + lane] = 0;
  #pragma unroll
  for (int m = 1; m < 64; m <<= 1) s += __shfl_xor(s, m, 64);
  if (lane == 0) e2[code] = s;
}

__global__ void k_zero(int* hist, double* dsum) {
  int t = threadIdx.x;
  if (t < NCODES) hist[t] = 0;
  if (t == 0) *dsum = 0.0;
}

// ---- one conv stage, 8 waves (2M x 4N), in-place, 2-ring streamed weights ----
template<int G0, bool RELU, bool ISSUE_NEXT>
__device__ __forceinline__ void stage(const char* __restrict__ wtp, u16* __restrict__ act,
                                      u16 (*wb)[20480], const float* bv,
                                      int oB, const u16* arow, int rbase,
                                      int wv, int lane, int lr, int lg,
                                      int t0, int T, bool edge) {
  f32x4 acc[5][3];
  #pragma unroll
  for (int m = 0; m < 5; ++m)
    #pragma unroll
    for (int n = 0; n < 3; ++n) acc[m][n] = f32x4{0.f, 0.f, 0.f, 0.f};
  #pragma unroll
  for (int cb = 0; cb < 6; ++cb) {
    const int g = G0 + cb;
    asm volatile("s_waitcnt vmcnt(0)" ::: "memory");    // own chunk-g granules (+older) done
    __builtin_amdgcn_sched_barrier(0);
    __builtin_amdgcn_s_barrier();                       // all waves' granules visible; prev reads done
    if (cb < 5 || ISSUE_NEXT) {
      const char* src = wtp + (size_t)(g + 1) * WSTRIDE + (wv * 5) * 1024 + lane * 16;
      char* dst = (char*)wb[(g + 1) & 1] + (wv * 5) * 1024;
      #pragma unroll
      for (int j = 0; j < 5; ++j) gld16(src + j * 1024, dst + j * 1024);
    }
    const u16* wq = wb[g & 1] + lg * 1536;
    #pragma unroll
    for (int k = 0; k < 3; ++k) {
      s16x8 af[5];
      #pragma unroll
      for (int m = 0; m < 5; ++m)
        af[m] = *(const s16x8*)(arow + (16 * m + k) * APITCH + cb * 32);
      #pragma unroll
      for (int nf = 0; nf < 3; ++nf) {
        s16x8 wf = *(const s16x8*)(wq + k * 6144 + (oB + nf * 16 + lr) * 8);
        #pragma unroll
        for (int m = 0; m < 5; ++m)
          acc[m][nf] = __builtin_amdgcn_mfma_f32_16x16x32_bf16(af[m], wf, acc[m][nf], 0, 0, 0);
      }
    }
  }
  __builtin_amdgcn_s_barrier();          // E1: all waves done reading act
  if (!edge) {
    #pragma unroll
    for (int m = 0; m < 5; ++m)
      #pragma unroll
      for (int nf = 0; nf < 3; ++nf) {
        int o = oB + nf * 16 + lr;
        #pragma unroll
        for (int r = 0; r < 4; ++r) {
          int row = rbase + 16 * m + lg * 4 + r;
          float v = acc[m][nf][r] + bv[nf];
          if (RELU) v = fmaxf(v, 0.f);
          act[row * APITCH + o] = f2b(v);
        }
      }
  } else {
    #pragma unroll
    for (int m = 0; m < 5; ++m)
      #pragma unroll
      for (int nf = 0; nf < 3; ++nf) {
        int o = oB + nf * 16 + lr;
        #pragma unroll
        for (int r = 0; r < 4; ++r) {
          int row = rbase + 16 * m + lg * 4 + r;
          int tok = t0 - HALO + row;
          float v = acc[m][nf][r] + bv[nf];
          if (RELU) v = fmaxf(v, 0.f);
          if (tok < 0 || tok >= T) v = 0.f;   // reference zero-pads every conv at sequence edges
          act[row * APITCH + o] = f2b(v);
        }
      }
  }
  asm volatile("s_waitcnt lgkmcnt(0)" ::: "memory");
  __builtin_amdgcn_s_barrier();          // E2: writes visible
}

// ---- fully fused, 512 threads (8 waves = 2/SIMD), 128 tokens/block, 1 block/CU ----
__global__ __launch_bounds__(512, 1) void k_fused(
    const char* __restrict__ xtp, const char* __restrict__ wtp,
    const float* __restrict__ eb1, const float* __restrict__ eb2,
    const float* __restrict__ db1, const float* __restrict__ db2, const float* __restrict__ db3,
    const char* __restrict__ embp, const float* __restrict__ e2,
    int* __restrict__ hist, double* __restrict__ dsum,
    float* __restrict__ xhat, int T) {
  __shared__ __align__(16) u16 act[AROWS * APITCH];   // 58,400 B
  __shared__ __align__(16) u16 wb[2][20480];          // 2 x 40,960 B ring
  __shared__ int hs[NCODES];
  __shared__ float wsum[8];
  const int tid = threadIdx.x;
  const int wv = tid >> 6, lane = tid & 63, lr = lane & 15, lg = lane >> 4;
  const int nw = wv & 3, mw = wv >> 2;
  const int bid = blockIdx.x;
  const int b = bid >> 6, tile = bid & 63;            // T/128 = 64 tiles per batch
  const int t0 = tile * TOK;
  const bool edge = (tile == 0) || (tile == 63);
  const int oB = nw * 48;
  const int rbase = 1 + mw * 64;                      // stage output rows [rbase, rbase+80)
  const u16* arow = act + (rbase - 1 + lr) * APITCH + lg * 8;
  if (tid < NCODES) hs[tid] = 0;

  float bvv[5][3];
  #pragma unroll
  for (int nf = 0; nf < 3; ++nf) {
    int o = oB + nf * 16 + lr;
    bvv[0][nf] = eb1[o]; bvv[1][nf] = eb2[o];
    bvv[2][nf] = db1[o]; bvv[3][nf] = db2[o]; bvv[4][nf] = db3[o];
  }

  // stage x rows t0-9 .. t0+136 (146 x 400B = 3650 x 16B granules)
  {
    const char* src = xtp + (size_t)(b * RPB + LEAD + t0 - HALO) * 400;
    #pragma unroll
    for (int s = 0; s < 8; ++s) {
      int c = tid + s * 512;
      if (c < AROWS * 25)
        gld16(src + (size_t)c * 16, (char*)act + (size_t)c * 16);
    }
  }
  // prologue: weight chunk 0 (chunk 1 issued inside step 0)
  {
    const char* s0 = wtp + (size_t)(wv * 5) * 1024 + lane * 16;
    char* d0 = (char*)wb[0] + (wv * 5) * 1024;
    #pragma unroll
    for (int j = 0; j < 5; ++j) gld16(s0 + j * 1024, d0 + j * 1024);
  }

  stage<0,  true,  true >(wtp, act, wb, bvv[0], oB, arow, rbase, wv, lane, lr, lg, t0, T, edge); // h1
  stage<6,  false, false>(wtp, act, wb, bvv[1], oB, arow, rbase, wv, lane, lr, lg, t0, T, edge); // z_e

  // ---- VQ on LDS z_e; 8 waves x 16 tokens; emb (2 x 25 granules) into wb[0]/wb[1] ----
  {
    #pragma unroll
    for (int j = 0; j < 4; ++j) {
      int c = wv + 8 * j;
      if (c < 25) {
        gld16(embp + c * 1024 + lane * 16, (char*)wb[0] + c * 1024);
        gld16(embp + 25600 + c * 1024 + lane * 16, (char*)wb[1] + c * 1024);
      }
    }
    asm volatile("s_waitcnt vmcnt(0)" ::: "memory");
    __builtin_amdgcn_sched_barrier(0);
    __builtin_amdgcn_s_barrier();

    const int row = HALO + wv * 16 + lr;
    f32x4 va[8];
    #pragma unroll
    for (int n = 0; n < 8; ++n) va[n] = f32x4{0.f, 0.f, 0.f, 0.f};
    #pragma unroll
    for (int cb = 0; cb < 6; ++cb) {
      s16x8 az = *(const s16x8*)(act + row * APITCH + cb * 32 + lg * 8);
      #pragma unroll
      for (int n = 0; n < 4; ++n) {
        s16x8 e1f = *(const s16x8*)(wb[0] + (n * 16 + lr) * APITCH + cb * 32 + lg * 8);
        va[n] = __builtin_amdgcn_mfma_f32_16x16x32_bf16(az, e1f, va[n], 0, 0, 0);
        s16x8 e2f = *(const s16x8*)(wb[1] + (n * 16 + lr) * APITCH + cb * 32 + lg * 8);
        va[n + 4] = __builtin_amdgcn_mfma_f32_16x16x32_bf16(az, e2f, va[n + 4], 0, 0, 0);
      }
    }
    float z2 = 0.f;
    const u16* zr = act + row * APITCH + lg * 48;
    #pragma unroll
    for (int j = 0; j < 48; j += 8) {
      s16x8 vv = *(const s16x8*)(zr + j);
      #pragma unroll
      for (int e = 0; e < 8; ++e) { float f = b2f((u16)vv[e]); z2 += f * f; }
    }
    z2 += __shfl_xor(z2, 16, 64);
    z2 += __shfl_xor(z2, 32, 64);
    float smin[4]; int imin[4];
    #pragma unroll
    for (int r = 0; r < 4; ++r) { smin[r] = 3.4e38f; imin[r] = 0; }
    #pragma unroll
    for (int n = 0; n < 8; ++n) {
      int code = n * 16 + lr;
      float ev = e2[code];
      #pragma unroll
      for (int r = 0; r < 4; ++r) {
        float sc = ev - 2.f * va[n][r];
        if (sc < smin[r]) { smin[r] = sc; imin[r] = code; }
      }
    }
    #pragma unroll
    for (int m = 1; m < 16; m <<= 1) {
      #pragma unroll
      for (int r = 0; r < 4; ++r) {
        float so = __shfl_xor(smin[r], m, 64);
        int io = __shfl_xor(imin[r], m, 64);
        if (so < smin[r] || (so == smin[r] && io < imin[r])) { smin[r] = so; imin[r] = io; }
      }
    }
    float z2t[4];
    #pragma unroll
    for (int r = 0; r < 4; ++r) z2t[r] = __shfl(z2, lg * 4 + r, 64);
    float dpart = 0.f;
    if (lr == 0) {
      #pragma unroll
      for (int r = 0; r < 4; ++r) {
        dpart += z2t[r] + smin[r];
        atomicAdd(&hs[imin[r]], 1);
      }
    }
    #pragma unroll
    for (int m = 1; m < 64; m <<= 1) dpart += __shfl_xor(dpart, m, 64);
    if (lane == 0) wsum[wv] = dpart;
    asm volatile("s_waitcnt lgkmcnt(0)" ::: "memory");
    __builtin_amdgcn_s_barrier();         // C: all VQ LDS traffic done
    // issue dec1 chunk 12 -> wb[0]
    {
      const char* s = wtp + (size_t)12 * WSTRIDE + (wv * 5) * 1024 + lane * 16;
      char* d = (char*)wb[0] + (wv * 5) * 1024;
      #pragma unroll
      for (int j = 0; j < 5; ++j) gld16(s + j * 1024, d + j * 1024);
    }
    if (tid == 0) {
      double tot = 0.0;
      #pragma unroll
      for (int w = 0; w < 8; ++w) tot += (double)wsum[w];
      atomicAdd(dsum, tot);
    }
    if (tid < NCODES && hs[tid] > 0) atomicAdd(&hist[tid], hs[tid]);
  }

  stage<12, true, true>(wtp, act, wb, bvv[2], oB, arow, rbase, wv, lane, lr, lg, t0, T, edge);  // dec1
  stage<18, true, true>(wtp, act, wb, bvv[3], oB, arow, rbase, wv, lane, lr, lg, t0, T, edge);  // dec2

  // ---- dec3 (chunks 24..29): own 64 rows per M-half, acc in regs ----
  f32x4 acc5[4][3];
  #pragma unroll
  for (int m = 0; m < 4; ++m)
    #pragma unroll
    for (int n = 0; n < 3; ++n) acc5[m][n] = f32x4{0.f, 0.f, 0.f, 0.f};
  {
    const u16* arow3 = act + (8 + mw * 64 + lr) * APITCH + lg * 8;
    #pragma unroll
    for (int cb = 0; cb < 6; ++cb) {
      const int g = 24 + cb;
      asm volatile("s_waitcnt vmcnt(0)" ::: "memory");
      __builtin_amdgcn_sched_barrier(0);
      __builtin_amdgcn_s_barrier();
      if (cb < 5) {
        const char* src = wtp + (size_t)(g + 1) * WSTRIDE + (wv * 5) * 1024 + lane * 16;
        char* dst = (char*)wb[(g + 1) & 1] + (wv * 5) * 1024;
        #pragma unroll
        for (int j = 0; j < 5; ++j) gld16(src + j * 1024, dst + j * 1024);
      }
      const u16* wq = wb[g & 1] + lg * 1536;
      #pragma unroll
      for (int k = 0; k < 3; ++k) {
        s16x8 af[4];
        #pragma unroll
        for (int m = 0; m < 4; ++m)
          af[m] = *(const s16x8*)(arow3 + (16 * m + k) * APITCH + cb * 32);
        #pragma unroll
        for (int nf = 0; nf < 3; ++nf) {
          s16x8 wf = *(const s16x8*)(wq + k * 6144 + (oB + nf * 16 + lr) * 8);
          #pragma unroll
          for (int m = 0; m < 4; ++m)
            acc5[m][nf] = __builtin_amdgcn_mfma_f32_16x16x32_bf16(af[m], wf, acc5[m][nf], 0, 0, 0);
        }
      }
    }
  }

  // ---- f32 (B,C,T) output via 2-pass LDS transpose (96 ch x 128 tok per pass) ----
  float* ft = (float*)act;                 // 96*130*4 = 49,920 B <= act
  float* dstb = xhat + (size_t)b * CCH * T + t0;
  #pragma unroll
  for (int p = 0; p < 2; ++p) {
    __builtin_amdgcn_s_barrier();          // p0: act reads done; p1: pass-0 stores consumed
    if ((nw >> 1) == p) {
      #pragma unroll
      for (int m = 0; m < 4; ++m)
        #pragma unroll
        for (int nf = 0; nf < 3; ++nf) {
          int o = (nw & 1) * 48 + nf * 16 + lr;
          #pragma unroll
          for (int r = 0; r < 4; ++r) {
            int tl = mw * 64 + 16 * m + lg * 4 + r;
            ft[o * 130 + tl] = acc5[m][nf][r] + bvv[4][nf];
          }
        }
    }
    asm volatile("s_waitcnt lgkmcnt(0)" ::: "memory");
    __builtin_amdgcn_s_barrier();
    #pragma unroll
    for (int i = 0; i < 24; ++i) {
      int s = tid + i * 512;
      int o = s >> 7, tl = s & 127;
      dstb[(size_t)(o + p * 96) * T + tl] = ft[o * 130 + tl];
    }
  }
}

__global__ __launch_bounds__(128) void k_fin(const int* __restrict__ hist,
                                             const double* __restrict__ dsum,
                                             float* __restrict__ out, int N, int ppos) {
  __shared__ float H[NCODES];
  int t = threadIdx.x;
  float p = (float)hist[t] / (float)N;
  H[t] = p * logf(p + 1e-10f);
  __syncthreads();
  if (t == 0) {
    float s = 0.f;
    for (int i = 0; i < NCODES; ++i) s += H[i];
    out[ppos] = expf(-s);
    out[0] = (float)(1.25 * (*dsum) / ((double)N * (double)CCH));
  }
}

extern "C" void kernel_launch(void* const* d_in, const int* in_sizes, int n_in,
                              void* d_out, int out_size, void* d_ws, size_t ws_size,
                              hipStream_t stream) {
  const int B = 16, T = 8192, N = B * T;
  const float* x   = (const float*)d_in[0];
  const float* ew1 = (const float*)d_in[1];
  const float* eb1 = (const float*)d_in[2];
  const float* ew2 = (const float*)d_in[3];
  const float* eb2 = (const float*)d_in[4];
  const float* emb = (const float*)d_in[5];
  const float* dw1 = (const float*)d_in[6];
  const float* db1 = (const float*)d_in[7];
  const float* dw2 = (const float*)d_in[8];
  const float* db2 = (const float*)d_in[9];
  const float* dw3 = (const float*)d_in[10];
  const float* db3 = (const float*)d_in[11];

  char* ws = (char*)d_ws;
  char*  xtp  = ws;                          // 16*8216*400 = 52,582,400
  char*  wtp  = ws + 52582400;               // 30 chunks * 40,960 = 1,228,800
  char*  embp = ws + 53811200;               // 51,200 valid + slack
  float* e2   = (float*)(ws + 53876736);
  int*   hist = (int*)(ws + 53877248);
  double* dsum = (double*)(ws + 53877760);

  const int wblocks = (3 * CCH * CCH + 255) / 256;          // 432
  k_wconv<<<wblocks, 256, 0, stream>>>(ew1, (u16*)wtp);
  k_wconv<<<wblocks, 256, 0, stream>>>(ew2, (u16*)wtp + 6 * 20480);
  k_wconv<<<wblocks, 256, 0, stream>>>(dw1, (u16*)wtp + 12 * 20480);
  k_wconv<<<wblocks, 256, 0, stream>>>(dw2, (u16*)wtp + 18 * 20480);
  k_wconv<<<wblocks, 256, 0, stream>>>(dw3, (u16*)wtp + 24 * 20480);
  k_emb<<<NCODES, 64, 0, stream>>>(emb, (u16*)embp, e2);
  k_zero<<<1, 256, 0, stream>>>(hist, dsum);
  k_padz<<<B, 256, 0, stream>>>((u16*)xtp);
  k_tin<<<B * 6 * (T / 32), 256, 0, stream>>>(x, (u16*)xtp, B, T);

  k_fused<<<B * (T / TOK), 512, 0, stream>>>(xtp, wtp, eb1, eb2, db1, db2, db3,
                                             embp, e2, hist, dsum, (float*)d_out + 1, T);
  k_fin<<<1, 128, 0, stream>>>(hist, dsum, (float*)d_out, N, out_size - 1);
}

// Round 13
// 273.624 us; speedup vs baseline: 1.3330x; 1.0244x over previous
//
#include <hip/hip_runtime.h>
#include <hip/hip_bf16.h>
#include <stdint.h>

typedef short s16x8 __attribute__((ext_vector_type(8)));
typedef float f32x4 __attribute__((ext_vector_type(4)));
typedef unsigned int u32;
typedef unsigned short u16;

#define CCH 192
#define APITCH 200     // u16 pitch of act rows (400 B)
#define NCODES 128
#define HALO 9
#define RPB 8216       // padded rows per batch in xtp: 12 lead + 8192 + 12 trail
#define LEAD 12
#define TOK 256        // tokens per block
#define AROWS 274      // staged rows: t0-9 .. t0+264
#define CHS 16384      // padded weight tap-chunk stride (12,288 valid)

__device__ __forceinline__ u16 f2b(float f) {
  u32 u = __builtin_bit_cast(u32, f);
  u = (u + 0x7fffu + ((u >> 16) & 1u)) >> 16;   // RNE
  return (u16)u;
}
__device__ __forceinline__ float b2f(u16 h) {
  return __builtin_bit_cast(float, ((u32)h) << 16);
}
__device__ __forceinline__ void gld16(const void* g, void* l) {
  __builtin_amdgcn_global_load_lds(
      (const __attribute__((address_space(1))) void*)g,
      (__attribute__((address_space(3))) void*)l, 16, 0, 0);
}

// ---- x (B,C,T) f32 -> xtp (padded rows, pitch 200) bf16 ----
__global__ __launch_bounds__(256) void k_tin(const float* __restrict__ x, u16* __restrict__ xtp,
                                             int B, int T) {
  __shared__ float tile[32][36];
  int nt = T >> 5;
  int bid = blockIdx.x;
  int b = bid / (6 * nt);
  int rem = bid % (6 * nt);
  int cb = rem / nt, tb = rem % nt;
  int tid = threadIdx.x;
  {
    int c = tid >> 3, seg = tid & 7;
    const float* src = x + ((size_t)b * CCH + cb * 32 + c) * T + tb * 32 + seg * 4;
    float4 v = *(const float4*)src;
    tile[c][seg * 4 + 0] = v.x; tile[c][seg * 4 + 1] = v.y;
    tile[c][seg * 4 + 2] = v.z; tile[c][seg * 4 + 3] = v.w;
  }
  __syncthreads();
  {
    int t = tid >> 3, cs = tid & 7;
    u16* dst = xtp + ((size_t)(b * RPB + LEAD + tb * 32 + t)) * APITCH + cb * 32 + cs * 4;
    ushort4 o;
    o.x = f2b(tile[cs * 4 + 0][t]); o.y = f2b(tile[cs * 4 + 1][t]);
    o.z = f2b(tile[cs * 4 + 2][t]); o.w = f2b(tile[cs * 4 + 3][t]);
    *(ushort4*)dst = o;
  }
}

// ---- zero the pad rows of xtp (12 lead + 12 trail per batch) ----
__global__ __launch_bounds__(256) void k_padz(u16* __restrict__ xtp) {
  int b = blockIdx.x;
  for (int i = threadIdx.x; i < 24 * 25; i += 256) {
    int r = i / 25, c = i - (i / 25) * 25;
    int row = (r < 12) ? r : (RPB - 12 + (r - 12));
    uint4 z = {0u, 0u, 0u, 0u};
    *(uint4*)((char*)xtp + ((size_t)(b * RPB + row)) * 400 + c * 16) = z;
  }
}

// ---- weights (O,I,3) f32 -> tap-chunks: chunk (cb,k) at byte (cb*3+k)*CHS, layout [lg][o][8] ----
__global__ __launch_bounds__(256) void k_wconv(const float* __restrict__ w, u16* __restrict__ dst) {
  int i = blockIdx.x * 256 + threadIdx.x;
  if (i >= 3 * CCH * CCH) return;
  int cb = i / 18432;
  int r = i - cb * 18432;
  int k = r / 6144;
  int r2 = r - k * 6144;
  int o = r2 / 32, il = r2 - o * 32;
  dst[(size_t)(cb * 3 + k) * (CHS / 2) + (il >> 3) * 1536 + o * 8 + (il & 7)] =
      f2b(w[(o * CCH + cb * 32 + il) * 3 + k]);
}

// ---- emb (K,C) f32 -> emb chunks [cb][lg][code][8] (8,192 B each) + ||e||^2 f32 ----
__global__ __launch_bounds__(64) void k_emb(const float* __restrict__ emb, u16* __restrict__ embp,
                                            float* __restrict__ e2) {
  int code = blockIdx.x, lane = threadIdx.x;
  float s = 0.f;
  for (int j = lane * 3; j < lane * 3 + 3; ++j) {
    float v = emb[code * CCH + j];
    int cb = j >> 5, il = j & 31;
    embp[(size_t)cb * 4096 + (il >> 3) * 1024 + code * 8 + (il & 7)] = f2b(v);
    s += v * v;
  }
  #pragma unroll
  for (int m = 1; m < 64; m <<= 1) s += __shfl_xor(s, m, 64);
  if (lane == 0) e2[code] = s;
}

__global__ void k_zero(int* hist, double* dsum) {
  int t = threadIdx.x;
  if (t < NCODES) hist[t] = 0;
  if (t == 0) *dsum = 0.0;
}

// ---- cooperative chunk loaders (512 threads) ----
__device__ __forceinline__ void issueW(const char* src, u16* dstb, int wv, int lane) {
  const char* s0 = src + wv * 2048 + lane * 16;
  char* d0 = (char*)dstb + wv * 2048 + lane * 16;
  gld16(s0, d0);
  gld16(s0 + 1024, d0 + 1024);
}
__device__ __forceinline__ void issueE(const char* src, u16* dstb, int tid) {
  gld16(src + tid * 16, (char*)dstb + tid * 16);
}

// ---- one conv phase: 18 tap-chunk steps, 2-ring, [vmcnt(0); bar; issue s+1; compute s] ----
// NEXT: 0 none, 1 issue weight chunk G0+18 at s==17, 2 issue emb chunk 0 at s==17.
template<int G0, int F, int NEXT>
__device__ __forceinline__ void conv_phase(const char* __restrict__ wtp, const char* __restrict__ embp,
                                           const u16* __restrict__ arow, u16 (*wb)[8192],
                                           int oB, int lr, int lg, int wv, int lane, int tid,
                                           f32x4 (&acc)[F][3]) {
  #pragma unroll 2
  for (int s = 0; s < 18; ++s) {
    asm volatile("s_waitcnt vmcnt(0)" ::: "memory");   // my chunk-s granules (issued at s-1) done
    __builtin_amdgcn_sched_barrier(0);
    __builtin_amdgcn_s_barrier();                      // all waves' granules visible; wb[(s+1)&1] free
    if (s < 17) issueW(wtp + (size_t)(G0 + s + 1) * CHS, wb[(s + 1) & 1], wv, lane);
    else if (NEXT == 1) issueW(wtp + (size_t)(G0 + 18) * CHS, wb[0], wv, lane);
    else if (NEXT == 2) issueE(embp, wb[0], tid);
    const int cb = s / 3, k = s - 3 * (s / 3);
    const u16* wq = wb[s & 1] + lg * 1536 + (oB + lr) * 8;
    const u16* ab = arow + k * APITCH + cb * 32;
    s16x8 af[F];
    #pragma unroll
    for (int m = 0; m < F; ++m)
      af[m] = *(const s16x8*)(ab + 16 * m * APITCH);
    #pragma unroll
    for (int nf = 0; nf < 3; ++nf) {
      s16x8 wf = *(const s16x8*)(wq + nf * 128);
      #pragma unroll
      for (int m = 0; m < F; ++m)
        acc[m][nf] = __builtin_amdgcn_mfma_f32_16x16x32_bf16(af[m], wf, acc[m][nf], 0, 0, 0);
    }
  }
}

// ---- in-place write-back of a conv stage's acc into act ----
template<int F, bool RELU>
__device__ __forceinline__ void writeback(u16* __restrict__ act, const f32x4 (&acc)[F][3],
                                          const float* bv, int oB, int lr, int lg, int rbase,
                                          int t0, int T, bool edge) {
  __builtin_amdgcn_s_barrier();          // E1: all waves done reading act
  if (!edge) {
    #pragma unroll
    for (int m = 0; m < F; ++m)
      #pragma unroll
      for (int nf = 0; nf < 3; ++nf) {
        int o = oB + nf * 16 + lr;
        #pragma unroll
        for (int r = 0; r < 4; ++r) {
          int row = rbase + 16 * m + lg * 4 + r;
          float v = acc[m][nf][r] + bv[nf];
          if (RELU) v = fmaxf(v, 0.f);
          act[row * APITCH + o] = f2b(v);
        }
      }
  } else {
    #pragma unroll
    for (int m = 0; m < F; ++m)
      #pragma unroll
      for (int nf = 0; nf < 3; ++nf) {
        int o = oB + nf * 16 + lr;
        #pragma unroll
        for (int r = 0; r < 4; ++r) {
          int row = rbase + 16 * m + lg * 4 + r;
          int tok = t0 - HALO + row;
          float v = acc[m][nf][r] + bv[nf];
          if (RELU) v = fmaxf(v, 0.f);
          if (tok < 0 || tok >= T) v = 0.f;   // reference zero-pads every conv at sequence edges
          act[row * APITCH + o] = f2b(v);
        }
      }
  }
  asm volatile("s_waitcnt lgkmcnt(0)" ::: "memory");
  __builtin_amdgcn_s_barrier();          // E2: writes visible
}

// ---- fully fused, 512 threads (8 waves), 256 tokens/block, tap-granular weight streaming ----
__global__ __launch_bounds__(512, 2) void k_fused(
    const char* __restrict__ xtp, const char* __restrict__ wtp,
    const float* __restrict__ eb1, const float* __restrict__ eb2,
    const float* __restrict__ db1, const float* __restrict__ db2, const float* __restrict__ db3,
    const char* __restrict__ embp, const float* __restrict__ e2,
    int* __restrict__ hist, double* __restrict__ dsum,
    float* __restrict__ xhat, int T) {
  __shared__ __align__(16) u16 act[AROWS * APITCH];   // 109,600 B
  __shared__ __align__(16) u16 wb[2][8192];           // 2 x 16,384 B tap-chunk ring
  __shared__ int hs[NCODES];
  __shared__ float wsum[8];
  const int tid = threadIdx.x;
  const int wv = tid >> 6, lane = tid & 63, lr = lane & 15, lg = lane >> 4;
  const int nw = wv & 3, mw = wv >> 2;
  const int bid = blockIdx.x;
  const int b = bid >> 5, tile = bid & 31;            // T/256 = 32 tiles per batch
  const int t0 = tile * TOK;
  const bool edge = (tile == 0) || (tile == 31);
  const int oB = nw * 48;
  const int rbase = 1 + mw * 128;                     // conv stage output rows [rbase, rbase+144)
  const u16* arow = act + (rbase - 1 + lr) * APITCH + lg * 8;
  if (tid < NCODES) hs[tid] = 0;

  float bvv[5][3];
  #pragma unroll
  for (int nf = 0; nf < 3; ++nf) {
    int o = oB + nf * 16 + lr;
    bvv[0][nf] = eb1[o]; bvv[1][nf] = eb2[o];
    bvv[2][nf] = db1[o]; bvv[3][nf] = db2[o]; bvv[4][nf] = db3[o];
  }

  // stage x rows t0-9 .. t0+264 (274 x 400B = 6850 x 16B granules)
  {
    const char* src = xtp + (size_t)(b * RPB + LEAD + t0 - HALO) * 400;
    #pragma unroll
    for (int s = 0; s < 14; ++s) {
      int c = tid + s * 512;
      if (c < AROWS * 25)
        gld16(src + (size_t)c * 16, (char*)act + (size_t)c * 16);
    }
  }
  // prologue: h1 tap-chunk 0 (chunk 1 issued inside step 0)
  issueW(wtp, wb[0], wv, lane);

  // ---- enc1 ----
  {
    f32x4 acc[9][3];
    #pragma unroll
    for (int m = 0; m < 9; ++m)
      #pragma unroll
      for (int n = 0; n < 3; ++n) acc[m][n] = f32x4{0.f, 0.f, 0.f, 0.f};
    conv_phase<0, 9, 1>(wtp, embp, arow, wb, oB, lr, lg, wv, lane, tid, acc);
    writeback<9, true>(act, acc, bvv[0], oB, lr, lg, rbase, t0, T, edge);
  }
  // ---- enc2 (z_e); issues emb chunk 0 at its last step ----
  {
    f32x4 acc[9][3];
    #pragma unroll
    for (int m = 0; m < 9; ++m)
      #pragma unroll
      for (int n = 0; n < 3; ++n) acc[m][n] = f32x4{0.f, 0.f, 0.f, 0.f};
    conv_phase<18, 9, 2>(wtp, embp, arow, wb, oB, lr, lg, wv, lane, tid, acc);
    writeback<9, false>(act, acc, bvv[1], oB, lr, lg, rbase, t0, T, edge);
  }

  // ---- VQ: 8 waves x 32 tokens (2 row-groups of 16); emb streamed through ring ----
  {
    f32x4 va0[8], va1[8];
    #pragma unroll
    for (int n = 0; n < 8; ++n) { va0[n] = f32x4{0.f,0.f,0.f,0.f}; va1[n] = f32x4{0.f,0.f,0.f,0.f}; }
    const int zr0 = 9 + wv * 32 + lr;
    #pragma unroll 2
    for (int s = 0; s < 6; ++s) {
      asm volatile("s_waitcnt vmcnt(0)" ::: "memory");
      __builtin_amdgcn_sched_barrier(0);
      __builtin_amdgcn_s_barrier();
      if (s < 5) issueE(embp + (s + 1) * 8192, wb[(s + 1) & 1], tid);
      else issueW(wtp + (size_t)36 * CHS, wb[0], wv, lane);   // dec1 chunk 0
      const u16* eq = wb[s & 1] + lg * 1024 + lr * 8;
      s16x8 az0 = *(const s16x8*)(act + zr0 * APITCH + s * 32 + lg * 8);
      s16x8 az1 = *(const s16x8*)(act + (zr0 + 16) * APITCH + s * 32 + lg * 8);
      #pragma unroll
      for (int nf = 0; nf < 8; ++nf) {
        s16x8 ef = *(const s16x8*)(eq + nf * 128);
        va0[nf] = __builtin_amdgcn_mfma_f32_16x16x32_bf16(az0, ef, va0[nf], 0, 0, 0);
        va1[nf] = __builtin_amdgcn_mfma_f32_16x16x32_bf16(az1, ef, va1[nf], 0, 0, 0);
      }
    }
    float e2v[8];
    #pragma unroll
    for (int nf = 0; nf < 8; ++nf) e2v[nf] = e2[nf * 16 + lr];
    float dpart = 0.f;
    #pragma unroll
    for (int rg = 0; rg < 2; ++rg) {
      float z2 = 0.f;
      const u16* zr = act + (zr0 + rg * 16) * APITCH + lg * 48;
      #pragma unroll
      for (int j = 0; j < 48; j += 8) {
        s16x8 vv = *(const s16x8*)(zr + j);
        #pragma unroll
        for (int e = 0; e < 8; ++e) { float f = b2f((u16)vv[e]); z2 += f * f; }
      }
      z2 += __shfl_xor(z2, 16, 64);
      z2 += __shfl_xor(z2, 32, 64);
      float smin[4]; int imin[4];
      #pragma unroll
      for (int r = 0; r < 4; ++r) { smin[r] = 3.4e38f; imin[r] = 0; }
      #pragma unroll
      for (int nf = 0; nf < 8; ++nf) {
        int code = nf * 16 + lr;
        #pragma unroll
        for (int r = 0; r < 4; ++r) {
          float sc = e2v[nf] - 2.f * (rg ? va1[nf][r] : va0[nf][r]);
          if (sc < smin[r]) { smin[r] = sc; imin[r] = code; }
        }
      }
      #pragma unroll
      for (int m = 1; m < 16; m <<= 1) {
        #pragma unroll
        for (int r = 0; r < 4; ++r) {
          float so = __shfl_xor(smin[r], m, 64);
          int io = __shfl_xor(imin[r], m, 64);
          if (so < smin[r] || (so == smin[r] && io < imin[r])) { smin[r] = so; imin[r] = io; }
        }
      }
      #pragma unroll
      for (int r = 0; r < 4; ++r) {
        float z2t = __shfl(z2, lg * 4 + r, 64);
        if (lr == 0) {
          dpart += z2t + smin[r];
          atomicAdd(&hs[imin[r]], 1);
        }
      }
    }
    #pragma unroll
    for (int m = 1; m < 64; m <<= 1) dpart += __shfl_xor(dpart, m, 64);
    if (lane == 0) wsum[wv] = dpart;
    asm volatile("s_waitcnt lgkmcnt(0)" ::: "memory");
    __builtin_amdgcn_s_barrier();        // all VQ LDS traffic done
    if (tid == 0) {
      double tot = 0.0;
      #pragma unroll
      for (int w = 0; w < 8; ++w) tot += (double)wsum[w];
      atomicAdd(dsum, tot);
    }
    if (tid < NCODES && hs[tid] > 0) atomicAdd(&hist[tid], hs[tid]);
  }

  // ---- dec1, dec2 ----
  {
    f32x4 acc[9][3];
    #pragma unroll
    for (int m = 0; m < 9; ++m)
      #pragma unroll
      for (int n = 0; n < 3; ++n) acc[m][n] = f32x4{0.f, 0.f, 0.f, 0.f};
    conv_phase<36, 9, 1>(wtp, embp, arow, wb, oB, lr, lg, wv, lane, tid, acc);
    writeback<9, true>(act, acc, bvv[2], oB, lr, lg, rbase, t0, T, edge);
  }
  {
    f32x4 acc[9][3];
    #pragma unroll
    for (int m = 0; m < 9; ++m)
      #pragma unroll
      for (int n = 0; n < 3; ++n) acc[m][n] = f32x4{0.f, 0.f, 0.f, 0.f};
    conv_phase<54, 9, 1>(wtp, embp, arow, wb, oB, lr, lg, wv, lane, tid, acc);
    writeback<9, true>(act, acc, bvv[3], oB, lr, lg, rbase, t0, T, edge);
  }

  // ---- dec3 (chunks 72..89): out rows [9, 265) = own 256 tokens, acc in regs ----
  f32x4 acc5[8][3];
  #pragma unroll
  for (int m = 0; m < 8; ++m)
    #pragma unroll
    for (int n = 0; n < 3; ++n) acc5[m][n] = f32x4{0.f, 0.f, 0.f, 0.f};
  {
    const u16* arow3 = act + (8 + mw * 128 + lr) * APITCH + lg * 8;
    conv_phase<72, 8, 0>(wtp, embp, arow3, wb, oB, lr, lg, wv, lane, tid, acc5);
  }

  // ---- f32 (B,C,T) output via 2-pass LDS transpose (96 ch x 256 tok per pass) ----
  float* ft = (float*)act;                 // 96*260*4 = 99,840 B <= act
  float* dstb = xhat + (size_t)b * CCH * T + t0;
  #pragma unroll
  for (int p = 0; p < 2; ++p) {
    __builtin_amdgcn_s_barrier();          // p0: act reads done; p1: pass-0 stores consumed
    if ((nw >> 1) == p) {
      #pragma unroll
      for (int m = 0; m < 8; ++m)
        #pragma unroll
        for (int nf = 0; nf < 3; ++nf) {
          int o = (nw & 1) * 48 + nf * 16 + lr;
          #pragma unroll
          for (int r = 0; r < 4; ++r) {
            int tl = mw * 128 + 16 * m + lg * 4 + r;
            ft[o * 260 + tl] = acc5[m][nf][r] + bvv[4][nf];
          }
        }
    }
    asm volatile("s_waitcnt lgkmcnt(0)" ::: "memory");
    __builtin_amdgcn_s_barrier();
    #pragma unroll
    for (int i = 0; i < 48; ++i) {
      int s = tid + i * 512;
      int o = s >> 8, tl = s & 255;
      dstb[(size_t)(o + p * 96) * T + tl] = ft[o * 260 + tl];
    }
  }
}

__global__ __launch_bounds__(128) void k_fin(const int* __restrict__ hist,
                                             const double* __restrict__ dsum,
                                             float* __restrict__ out, int N, int ppos) {
  __shared__ float H[NCODES];
  int t = threadIdx.x;
  float p = (float)hist[t] / (float)N;
  H[t] = p * logf(p + 1e-10f);
  __syncthreads();
  if (t == 0) {
    float s = 0.f;
    for (int i = 0; i < NCODES; ++i) s += H[i];
    out[ppos] = expf(-s);
    out[0] = (float)(1.25 * (*dsum) / ((double)N * (double)CCH));
  }
}

extern "C" void kernel_launch(void* const* d_in, const int* in_sizes, int n_in,
                              void* d_out, int out_size, void* d_ws, size_t ws_size,
                              hipStream_t stream) {
  const int B = 16, T = 8192, N = B * T;
  const float* x   = (const float*)d_in[0];
  const float* ew1 = (const float*)d_in[1];
  const float* eb1 = (const float*)d_in[2];
  const float* ew2 = (const float*)d_in[3];
  const float* eb2 = (const float*)d_in[4];
  const float* emb = (const float*)d_in[5];
  const float* dw1 = (const float*)d_in[6];
  const float* db1 = (const float*)d_in[7];
  const float* dw2 = (const float*)d_in[8];
  const float* db2 = (const float*)d_in[9];
  const float* dw3 = (const float*)d_in[10];
  const float* db3 = (const float*)d_in[11];

  char* ws = (char*)d_ws;
  char*  xtp  = ws;                           // 16*8216*400 = 52,582,400
  char*  wtp  = ws + 52583424;                // 90 tap-chunks * 16,384 = 1,474,560
  char*  embp = ws + 54057984;                // 6 * 8,192 = 49,152
  float* e2   = (float*)(ws + 54107136);
  int*   hist = (int*)(ws + 54107648);
  double* dsum = (double*)(ws + 54108160);

  const int wblocks = (3 * CCH * CCH + 255) / 256;          // 432
  const int TCH = 18 * (CHS / 2);                           // u16 per tensor = 147,456
  k_wconv<<<wblocks, 256, 0, stream>>>(ew1, (u16*)wtp);
  k_wconv<<<wblocks, 256, 0, stream>>>(ew2, (u16*)wtp + TCH);
  k_wconv<<<wblocks, 256, 0, stream>>>(dw1, (u16*)wtp + 2 * TCH);
  k_wconv<<<wblocks, 256, 0, stream>>>(dw2, (u16*)wtp + 3 * TCH);
  k_wconv<<<wblocks, 256, 0, stream>>>(dw3, (u16*)wtp + 4 * TCH);
  k_emb<<<NCODES, 64, 0, stream>>>(emb, (u16*)embp, e2);
  k_zero<<<1, 256, 0, stream>>>(hist, dsum);
  k_padz<<<B, 256, 0, stream>>>((u16*)xtp);
  k_tin<<<B * 6 * (T / 32), 256, 0, stream>>>(x, (u16*)xtp, B, T);

  k_fused<<<B * (T / TOK), 512, 0, stream>>>(xtp, wtp, eb1, eb2, db1, db2, db3,
                                             embp, e2, hist, dsum, (float*)d_out + 1, T);
  k_fin<<<1, 128, 0, stream>>>(hist, dsum, (float*)d_out, N, out_size - 1);
}

// Round 14
// 235.326 us; speedup vs baseline: 1.5500x; 1.1627x over previous
//
#include <hip/hip_runtime.h>
#include <hip/hip_bf16.h>
#include <stdint.h>

typedef short s16x8 __attribute__((ext_vector_type(8)));
typedef float f32x4 __attribute__((ext_vector_type(4)));
typedef unsigned int u32;
typedef unsigned short u16;

#define CCH 192
#define APITCH 200     // u16 pitch of act rows (400 B)
#define NCODES 128
#define HALO 9
#define RPB 8216       // padded rows per batch in xtp: 12 lead + 8192 + 12 trail
#define LEAD 12
#define TOK 256        // tokens per block
#define AROWS 274      // staged rows: t0-9 .. t0+264
#define CHS 16384      // padded weight tap-chunk stride (12,288 valid)

__device__ __forceinline__ u16 f2b(float f) {
  u32 u = __builtin_bit_cast(u32, f);
  u = (u + 0x7fffu + ((u >> 16) & 1u)) >> 16;   // RNE
  return (u16)u;
}
__device__ __forceinline__ float b2f(u16 h) {
  return __builtin_bit_cast(float, ((u32)h) << 16);
}
__device__ __forceinline__ void gld16(const void* g, void* l) {
  __builtin_amdgcn_global_load_lds(
      (const __attribute__((address_space(1))) void*)g,
      (__attribute__((address_space(3))) void*)l, 16, 0, 0);
}

// ---- x (B,C,T) f32 -> xtp (padded rows, pitch 200) bf16 ----
__global__ __launch_bounds__(256) void k_tin(const float* __restrict__ x, u16* __restrict__ xtp,
                                             int B, int T) {
  __shared__ float tile[32][36];
  int nt = T >> 5;
  int bid = blockIdx.x;
  int b = bid / (6 * nt);
  int rem = bid % (6 * nt);
  int cb = rem / nt, tb = rem % nt;
  int tid = threadIdx.x;
  {
    int c = tid >> 3, seg = tid & 7;
    const float* src = x + ((size_t)b * CCH + cb * 32 + c) * T + tb * 32 + seg * 4;
    float4 v = *(const float4*)src;
    tile[c][seg * 4 + 0] = v.x; tile[c][seg * 4 + 1] = v.y;
    tile[c][seg * 4 + 2] = v.z; tile[c][seg * 4 + 3] = v.w;
  }
  __syncthreads();
  {
    int t = tid >> 3, cs = tid & 7;
    u16* dst = xtp + ((size_t)(b * RPB + LEAD + tb * 32 + t)) * APITCH + cb * 32 + cs * 4;
    ushort4 o;
    o.x = f2b(tile[cs * 4 + 0][t]); o.y = f2b(tile[cs * 4 + 1][t]);
    o.z = f2b(tile[cs * 4 + 2][t]); o.w = f2b(tile[cs * 4 + 3][t]);
    *(ushort4*)dst = o;
  }
}

// ---- zero the pad rows of xtp (12 lead + 12 trail per batch) ----
__global__ __launch_bounds__(256) void k_padz(u16* __restrict__ xtp) {
  int b = blockIdx.x;
  for (int i = threadIdx.x; i < 24 * 25; i += 256) {
    int r = i / 25, c = i - (i / 25) * 25;
    int row = (r < 12) ? r : (RPB - 12 + (r - 12));
    uint4 z = {0u, 0u, 0u, 0u};
    *(uint4*)((char*)xtp + ((size_t)(b * RPB + row)) * 400 + c * 16) = z;
  }
}

// ---- weights (O,I,3) f32 -> tap-chunks: chunk (cb,k) at byte (cb*3+k)*CHS, layout [lg][o][8] ----
__global__ __launch_bounds__(256) void k_wconv(const float* __restrict__ w, u16* __restrict__ dst) {
  int i = blockIdx.x * 256 + threadIdx.x;
  if (i >= 3 * CCH * CCH) return;
  int cb = i / 18432;
  int r = i - cb * 18432;
  int k = r / 6144;
  int r2 = r - k * 6144;
  int o = r2 / 32, il = r2 - o * 32;
  dst[(size_t)(cb * 3 + k) * (CHS / 2) + (il >> 3) * 1536 + o * 8 + (il & 7)] =
      f2b(w[(o * CCH + cb * 32 + il) * 3 + k]);
}

// ---- emb (K,C) f32 -> emb chunks [cb][lg][code][8] (8,192 B each) + ||e||^2 f32 ----
__global__ __launch_bounds__(64) void k_emb(const float* __restrict__ emb, u16* __restrict__ embp,
                                            float* __restrict__ e2) {
  int code = blockIdx.x, lane = threadIdx.x;
  float s = 0.f;
  for (int j = lane * 3; j < lane * 3 + 3; ++j) {
    float v = emb[code * CCH + j];
    int cb = j >> 5, il = j & 31;
    embp[(size_t)cb * 4096 + (il >> 3) * 1024 + code * 8 + (il & 7)] = f2b(v);
    s += v * v;
  }
  #pragma unroll
  for (int m = 1; m < 64; m <<= 1) s += __shfl_xor(s, m, 64);
  if (lane == 0) e2[code] = s;
}

__global__ void k_zero(int* hist, double* dsum) {
  int t = threadIdx.x;
  if (t < NCODES) hist[t] = 0;
  if (t == 0) *dsum = 0.0;
}

// ---- cooperative chunk loaders (512 threads) ----
__device__ __forceinline__ void issueW(const char* src, u16* dstb, int wv, int lane) {
  const char* s0 = src + wv * 2048 + lane * 16;
  char* d0 = (char*)dstb + wv * 2048 + lane * 16;
  gld16(s0, d0);
  gld16(s0 + 1024, d0 + 1024);
}
__device__ __forceinline__ void issueE(const char* src, u16* dstb, int tid) {
  gld16(src + tid * 16, (char*)dstb + tid * 16);
}

// ---- asm LDS loads (cannot be sunk by the scheduler; lgkmcnt counted by hand) ----
template<int F, int S, int M>
__device__ __forceinline__ void af_load(u32 aaddr, s16x8 (&a)[2][F]) {
  constexpr int cb = S / 3, k = S - 3 * (S / 3);
  constexpr int imm = (16 * M + k) * 400 + cb * 64;
  asm volatile("ds_read_b128 %0, %1 offset:%2" : "=v"(a[S & 1][M]) : "v"(aaddr), "i"(imm));
  if constexpr (M + 1 < F) af_load<F, S, M + 1>(aaddr, a);
}
template<int NF>
__device__ __forceinline__ void wf_load(u32 wq, s16x8 (&wf)[3]) {
  asm volatile("ds_read_b128 %0, %1 offset:%2" : "=v"(wf[NF]) : "v"(wq), "i"(NF * 256));
  if constexpr (NF + 1 < 3) wf_load<NF + 1>(wq, wf);
}

// ---- one conv step: barrier (wf chunk S ready) -> issue S+1 -> wf(S) + af-prefetch(S+1)
//      -> lgkmcnt(F) [wf done, af(S+1) in flight under the MFMAs] -> 3F MFMAs on af(S) ----
template<int G0, int F, int NEXT, int S>
__device__ __forceinline__ void cstep(const char* __restrict__ wtp, const char* __restrict__ embp,
                                      u16 (*wb)[8192], u32 aaddr, u32 wq0, u32 wq1,
                                      int wv, int lane, int tid,
                                      s16x8 (&a)[2][F], f32x4 (&acc)[F][3]) {
  asm volatile("s_waitcnt vmcnt(0)" ::: "memory");   // my chunk-S granules (issued at S-1) done
  __builtin_amdgcn_sched_barrier(0);
  __builtin_amdgcn_s_barrier();                      // all waves' granules visible; wb[(S+1)&1] free
  if constexpr (S < 17) issueW(wtp + (size_t)(G0 + S + 1) * CHS, wb[(S + 1) & 1], wv, lane);
  else if constexpr (NEXT == 1) issueW(wtp + (size_t)(G0 + 18) * CHS, wb[0], wv, lane);
  else if constexpr (NEXT == 2) issueE(embp, wb[0], tid);
  if constexpr (S == 0) af_load<F, 0, 0>(aaddr, a);  // first-step af (act ready after barrier)
  s16x8 wf[3];
  wf_load<0>((S & 1) ? wq1 : wq0, wf);
  if constexpr (S < 17) {
    af_load<F, S + 1, 0>(aaddr, a);                  // prefetch next step's A frags
    if constexpr (F == 9) asm volatile("s_waitcnt lgkmcnt(9)" ::: "memory");
    else                  asm volatile("s_waitcnt lgkmcnt(8)" ::: "memory");
  } else {
    asm volatile("s_waitcnt lgkmcnt(0)" ::: "memory");
  }
  __builtin_amdgcn_sched_barrier(0);                 // MFMAs stay below the wait (rule #18)
  #pragma unroll
  for (int nf = 0; nf < 3; ++nf)
    #pragma unroll
    for (int m = 0; m < F; ++m)
      acc[m][nf] = __builtin_amdgcn_mfma_f32_16x16x32_bf16(a[S & 1][m], wf[nf], acc[m][nf], 0, 0, 0);
  if constexpr (S + 1 < 18)
    cstep<G0, F, NEXT, S + 1>(wtp, embp, wb, aaddr, wq0, wq1, wv, lane, tid, a, acc);
}

template<int G0, int F, int NEXT>
__device__ __forceinline__ void conv_phase(const char* __restrict__ wtp, const char* __restrict__ embp,
                                           u16 (*wb)[8192], u32 aaddr, u32 wq0, u32 wq1,
                                           int wv, int lane, int tid, f32x4 (&acc)[F][3]) {
  s16x8 a[2][F];
  cstep<G0, F, NEXT, 0>(wtp, embp, wb, aaddr, wq0, wq1, wv, lane, tid, a, acc);
}

// ---- in-place write-back of a conv stage's acc into act ----
template<int F, bool RELU>
__device__ __forceinline__ void writeback(u16* __restrict__ act, const f32x4 (&acc)[F][3],
                                          const float* bv, int oB, int lr, int lg, int rbase,
                                          int t0, int T, bool edge) {
  __builtin_amdgcn_s_barrier();          // E1: all waves done reading act
  if (!edge) {
    #pragma unroll
    for (int m = 0; m < F; ++m)
      #pragma unroll
      for (int nf = 0; nf < 3; ++nf) {
        int o = oB + nf * 16 + lr;
        #pragma unroll
        for (int r = 0; r < 4; ++r) {
          int row = rbase + 16 * m + lg * 4 + r;
          float v = acc[m][nf][r] + bv[nf];
          if (RELU) v = fmaxf(v, 0.f);
          act[row * APITCH + o] = f2b(v);
        }
      }
  } else {
    #pragma unroll
    for (int m = 0; m < F; ++m)
      #pragma unroll
      for (int nf = 0; nf < 3; ++nf) {
        int o = oB + nf * 16 + lr;
        #pragma unroll
        for (int r = 0; r < 4; ++r) {
          int row = rbase + 16 * m + lg * 4 + r;
          int tok = t0 - HALO + row;
          float v = acc[m][nf][r] + bv[nf];
          if (RELU) v = fmaxf(v, 0.f);
          if (tok < 0 || tok >= T) v = 0.f;   // reference zero-pads every conv at sequence edges
          act[row * APITCH + o] = f2b(v);
        }
      }
  }
  asm volatile("s_waitcnt lgkmcnt(0)" ::: "memory");
  __builtin_amdgcn_s_barrier();          // E2: writes visible
}

// ---- fully fused, 512 threads (8 waves), 256 tokens/block, tap-granular weight streaming ----
__global__ __launch_bounds__(512, 1) void k_fused(
    const char* __restrict__ xtp, const char* __restrict__ wtp,
    const float* __restrict__ eb1, const float* __restrict__ eb2,
    const float* __restrict__ db1, const float* __restrict__ db2, const float* __restrict__ db3,
    const char* __restrict__ embp, const float* __restrict__ e2,
    int* __restrict__ hist, double* __restrict__ dsum,
    float* __restrict__ xhat, int T) {
  __shared__ __align__(16) u16 act[AROWS * APITCH];   // 109,600 B
  __shared__ __align__(16) u16 wb[2][8192];           // 2 x 16,384 B tap-chunk ring
  __shared__ int hs[NCODES];
  __shared__ float wsum[8];
  const int tid = threadIdx.x;
  const int wv = tid >> 6, lane = tid & 63, lr = lane & 15, lg = lane >> 4;
  const int nw = wv & 3, mw = wv >> 2;
  const int bid = blockIdx.x;
  const int b = bid >> 5, tile = bid & 31;            // T/256 = 32 tiles per batch
  const int t0 = tile * TOK;
  const bool edge = (tile == 0) || (tile == 31);
  const int oB = nw * 48;
  const int rbase = 1 + mw * 128;                     // conv stage output rows [rbase, rbase+144)
  if (tid < NCODES) hs[tid] = 0;

  const u32 aaddr = (u32)(uintptr_t)act + (u32)(((rbase - 1 + lr) * APITCH + lg * 8) * 2);
  const u32 wq0 = (u32)(uintptr_t)wb[0] + (u32)((lg * 1536 + (oB + lr) * 8) * 2);
  const u32 wq1 = wq0 + 16384u;

  float bvv[5][3];
  #pragma unroll
  for (int nf = 0; nf < 3; ++nf) {
    int o = oB + nf * 16 + lr;
    bvv[0][nf] = eb1[o]; bvv[1][nf] = eb2[o];
    bvv[2][nf] = db1[o]; bvv[3][nf] = db2[o]; bvv[4][nf] = db3[o];
  }

  // stage x rows t0-9 .. t0+264 (274 x 400B = 6850 x 16B granules)
  {
    const char* src = xtp + (size_t)(b * RPB + LEAD + t0 - HALO) * 400;
    #pragma unroll
    for (int s = 0; s < 14; ++s) {
      int c = tid + s * 512;
      if (c < AROWS * 25)
        gld16(src + (size_t)c * 16, (char*)act + (size_t)c * 16);
    }
  }
  // prologue: h1 tap-chunk 0 (chunk 1 issued inside step 0)
  issueW(wtp, wb[0], wv, lane);

  // ---- enc1 ----
  {
    f32x4 acc[9][3];
    #pragma unroll
    for (int m = 0; m < 9; ++m)
      #pragma unroll
      for (int n = 0; n < 3; ++n) acc[m][n] = f32x4{0.f, 0.f, 0.f, 0.f};
    conv_phase<0, 9, 1>(wtp, embp, wb, aaddr, wq0, wq1, wv, lane, tid, acc);
    writeback<9, true>(act, acc, bvv[0], oB, lr, lg, rbase, t0, T, edge);
  }
  // ---- enc2 (z_e); issues emb chunk 0 at its last step ----
  {
    f32x4 acc[9][3];
    #pragma unroll
    for (int m = 0; m < 9; ++m)
      #pragma unroll
      for (int n = 0; n < 3; ++n) acc[m][n] = f32x4{0.f, 0.f, 0.f, 0.f};
    conv_phase<18, 9, 2>(wtp, embp, wb, aaddr, wq0, wq1, wv, lane, tid, acc);
    writeback<9, false>(act, acc, bvv[1], oB, lr, lg, rbase, t0, T, edge);
  }

  // ---- VQ: 8 waves x 32 tokens (2 row-groups of 16); emb streamed through ring ----
  {
    f32x4 va0[8], va1[8];
    #pragma unroll
    for (int n = 0; n < 8; ++n) { va0[n] = f32x4{0.f,0.f,0.f,0.f}; va1[n] = f32x4{0.f,0.f,0.f,0.f}; }
    const int zr0 = 9 + wv * 32 + lr;
    #pragma unroll 2
    for (int s = 0; s < 6; ++s) {
      asm volatile("s_waitcnt vmcnt(0)" ::: "memory");
      __builtin_amdgcn_sched_barrier(0);
      __builtin_amdgcn_s_barrier();
      if (s < 5) issueE(embp + (s + 1) * 8192, wb[(s + 1) & 1], tid);
      else issueW(wtp + (size_t)36 * CHS, wb[0], wv, lane);   // dec1 chunk 0
      const u16* eq = wb[s & 1] + lg * 1024 + lr * 8;
      s16x8 az0 = *(const s16x8*)(act + zr0 * APITCH + s * 32 + lg * 8);
      s16x8 az1 = *(const s16x8*)(act + (zr0 + 16) * APITCH + s * 32 + lg * 8);
      #pragma unroll
      for (int nf = 0; nf < 8; ++nf) {
        s16x8 ef = *(const s16x8*)(eq + nf * 128);
        va0[nf] = __builtin_amdgcn_mfma_f32_16x16x32_bf16(az0, ef, va0[nf], 0, 0, 0);
        va1[nf] = __builtin_amdgcn_mfma_f32_16x16x32_bf16(az1, ef, va1[nf], 0, 0, 0);
      }
    }
    float e2v[8];
    #pragma unroll
    for (int nf = 0; nf < 8; ++nf) e2v[nf] = e2[nf * 16 + lr];
    float dpart = 0.f;
    #pragma unroll
    for (int rg = 0; rg < 2; ++rg) {
      float z2 = 0.f;
      const u16* zr = act + (zr0 + rg * 16) * APITCH + lg * 48;
      #pragma unroll
      for (int j = 0; j < 48; j += 8) {
        s16x8 vv = *(const s16x8*)(zr + j);
        #pragma unroll
        for (int e = 0; e < 8; ++e) { float f = b2f((u16)vv[e]); z2 += f * f; }
      }
      z2 += __shfl_xor(z2, 16, 64);
      z2 += __shfl_xor(z2, 32, 64);
      float smin[4]; int imin[4];
      #pragma unroll
      for (int r = 0; r < 4; ++r) { smin[r] = 3.4e38f; imin[r] = 0; }
      #pragma unroll
      for (int nf = 0; nf < 8; ++nf) {
        int code = nf * 16 + lr;
        #pragma unroll
        for (int r = 0; r < 4; ++r) {
          float sc = e2v[nf] - 2.f * (rg ? va1[nf][r] : va0[nf][r]);
          if (sc < smin[r]) { smin[r] = sc; imin[r] = code; }
        }
      }
      #pragma unroll
      for (int m = 1; m < 16; m <<= 1) {
        #pragma unroll
        for (int r = 0; r < 4; ++r) {
          float so = __shfl_xor(smin[r], m, 64);
          int io = __shfl_xor(imin[r], m, 64);
          if (so < smin[r] || (so == smin[r] && io < imin[r])) { smin[r] = so; imin[r] = io; }
        }
      }
      #pragma unroll
      for (int r = 0; r < 4; ++r) {
        float z2t = __shfl(z2, lg * 4 + r, 64);
        if (lr == 0) {
          dpart += z2t + smin[r];
          atomicAdd(&hs[imin[r]], 1);
        }
      }
    }
    #pragma unroll
    for (int m = 1; m < 64; m <<= 1) dpart += __shfl_xor(dpart, m, 64);
    if (lane == 0) wsum[wv] = dpart;
    asm volatile("s_waitcnt lgkmcnt(0)" ::: "memory");
    __builtin_amdgcn_s_barrier();        // all VQ LDS traffic done
    if (tid == 0) {
      double tot = 0.0;
      #pragma unroll
      for (int w = 0; w < 8; ++w) tot += (double)wsum[w];
      atomicAdd(dsum, tot);
    }
    if (tid < NCODES && hs[tid] > 0) atomicAdd(&hist[tid], hs[tid]);
  }

  // ---- dec1, dec2 ----
  {
    f32x4 acc[9][3];
    #pragma unroll
    for (int m = 0; m < 9; ++m)
      #pragma unroll
      for (int n = 0; n < 3; ++n) acc[m][n] = f32x4{0.f, 0.f, 0.f, 0.f};
    conv_phase<36, 9, 1>(wtp, embp, wb, aaddr, wq0, wq1, wv, lane, tid, acc);
    writeback<9, true>(act, acc, bvv[2], oB, lr, lg, rbase, t0, T, edge);
  }
  {
    f32x4 acc[9][3];
    #pragma unroll
    for (int m = 0; m < 9; ++m)
      #pragma unroll
      for (int n = 0; n < 3; ++n) acc[m][n] = f32x4{0.f, 0.f, 0.f, 0.f};
    conv_phase<54, 9, 1>(wtp, embp, wb, aaddr, wq0, wq1, wv, lane, tid, acc);
    writeback<9, true>(act, acc, bvv[3], oB, lr, lg, rbase, t0, T, edge);
  }

  // ---- dec3 (chunks 72..89): out rows [9, 265) = own 256 tokens, acc in regs ----
  f32x4 acc5[8][3];
  #pragma unroll
  for (int m = 0; m < 8; ++m)
    #pragma unroll
    for (int n = 0; n < 3; ++n) acc5[m][n] = f32x4{0.f, 0.f, 0.f, 0.f};
  {
    const u32 aaddr3 = (u32)(uintptr_t)act + (u32)(((8 + mw * 128 + lr) * APITCH + lg * 8) * 2);
    conv_phase<72, 8, 0>(wtp, embp, wb, aaddr3, wq0, wq1, wv, lane, tid, acc5);
  }

  // ---- f32 (B,C,T) output via 2-pass LDS transpose (96 ch x 256 tok per pass) ----
  float* ft = (float*)act;                 // 96*260*4 = 99,840 B <= act
  float* dstb = xhat + (size_t)b * CCH * T + t0;
  #pragma unroll
  for (int p = 0; p < 2; ++p) {
    __builtin_amdgcn_s_barrier();          // p0: act reads done; p1: pass-0 stores consumed
    if ((nw >> 1) == p) {
      #pragma unroll
      for (int m = 0; m < 8; ++m)
        #pragma unroll
        for (int nf = 0; nf < 3; ++nf) {
          int o = (nw & 1) * 48 + nf * 16 + lr;
          #pragma unroll
          for (int r = 0; r < 4; ++r) {
            int tl = mw * 128 + 16 * m + lg * 4 + r;
            ft[o * 260 + tl] = acc5[m][nf][r] + bvv[4][nf];
          }
        }
    }
    asm volatile("s_waitcnt lgkmcnt(0)" ::: "memory");
    __builtin_amdgcn_s_barrier();
    #pragma unroll
    for (int i = 0; i < 48; ++i) {
      int s = tid + i * 512;
      int o = s >> 8, tl = s & 255;
      dstb[(size_t)(o + p * 96) * T + tl] = ft[o * 260 + tl];
    }
  }
}

__global__ __launch_bounds__(128) void k_fin(const int* __restrict__ hist,
                                             const double* __restrict__ dsum,
                                             float* __restrict__ out, int N, int ppos) {
  __shared__ float H[NCODES];
  int t = threadIdx.x;
  float p = (float)hist[t] / (float)N;
  H[t] = p * logf(p + 1e-10f);
  __syncthreads();
  if (t == 0) {
    float s = 0.f;
    for (int i = 0; i < NCODES; ++i) s += H[i];
    out[ppos] = expf(-s);
    out[0] = (float)(1.25 * (*dsum) / ((double)N * (double)CCH));
  }
}

extern "C" void kernel_launch(void* const* d_in, const int* in_sizes, int n_in,
                              void* d_out, int out_size, void* d_ws, size_t ws_size,
                              hipStream_t stream) {
  const int B = 16, T = 8192, N = B * T;
  const float* x   = (const float*)d_in[0];
  const float* ew1 = (const float*)d_in[1];
  const float* eb1 = (const float*)d_in[2];
  const float* ew2 = (const float*)d_in[3];
  const float* eb2 = (const float*)d_in[4];
  const float* emb = (const float*)d_in[5];
  const float* dw1 = (const float*)d_in[6];
  const float* db1 = (const float*)d_in[7];
  const float* dw2 = (const float*)d_in[8];
  const float* db2 = (const float*)d_in[9];
  const float* dw3 = (const float*)d_in[10];
  const float* db3 = (const float*)d_in[11];

  char* ws = (char*)d_ws;
  char*  xtp  = ws;                           // 16*8216*400 = 52,582,400
  char*  wtp  = ws + 52583424;                // 90 tap-chunks * 16,384 = 1,474,560
  char*  embp = ws + 54057984;                // 6 * 8,192 = 49,152
  float* e2   = (float*)(ws + 54107136);
  int*   hist = (int*)(ws + 54107648);
  double* dsum = (double*)(ws + 54108160);

  const int wblocks = (3 * CCH * CCH + 255) / 256;          // 432
  const int TCH = 18 * (CHS / 2);                           // u16 per tensor = 147,456
  k_wconv<<<wblocks, 256, 0, stream>>>(ew1, (u16*)wtp);
  k_wconv<<<wblocks, 256, 0, stream>>>(ew2, (u16*)wtp + TCH);
  k_wconv<<<wblocks, 256, 0, stream>>>(dw1, (u16*)wtp + 2 * TCH);
  k_wconv<<<wblocks, 256, 0, stream>>>(dw2, (u16*)wtp + 3 * TCH);
  k_wconv<<<wblocks, 256, 0, stream>>>(dw3, (u16*)wtp + 4 * TCH);
  k_emb<<<NCODES, 64, 0, stream>>>(emb, (u16*)embp, e2);
  k_zero<<<1, 256, 0, stream>>>(hist, dsum);
  k_padz<<<B, 256, 0, stream>>>((u16*)xtp);
  k_tin<<<B * 6 * (T / 32), 256, 0, stream>>>(x, (u16*)xtp, B, T);

  k_fused<<<B * (T / TOK), 512, 0, stream>>>(xtp, wtp, eb1, eb2, db1, db2, db3,
                                             embp, e2, hist, dsum, (float*)d_out + 1, T);
  k_fin<<<1, 128, 0, stream>>>(hist, dsum, (float*)d_out, N, out_size - 1);
}